// Round 20
// baseline (222.340 us; speedup 1.0000x reference)
//
#include <hip/hip_runtime.h>
#include <hip/hip_bf16.h>

#define B_N 16
#define LP_N 1024
#define LQ_N 1024
#define H_N 1024

typedef unsigned short u16;
typedef __attribute__((ext_vector_type(8))) _Float16 f16x8;
typedef __attribute__((ext_vector_type(4))) float f32x4;

__device__ __forceinline__ u16 f2h(float x) {
    _Float16 h = (_Float16)x;
    return *(u16*)&h;
}
__device__ __forceinline__ float h2f(u16 u) {
    _Float16 h;
    *(u16*)&h = u;
    return (float)h;
}

__device__ __forceinline__ void load_lds16(const u16* g, u16* l) {
    __builtin_amdgcn_global_load_lds(
        (const __attribute__((address_space(1))) void*)g,
        (__attribute__((address_space(3))) void*)l, 16, 0, 0);
}

#define MFMA_F16(a, b, c) __builtin_amdgcn_mfma_f32_16x16x32_f16(a, b, c, 0, 0, 0)
#define VMW0()  asm volatile("s_waitcnt vmcnt(0)" ::: "memory")
#define VMW2()  asm volatile("s_waitcnt vmcnt(2)" ::: "memory")
#define VMW4()  asm volatile("s_waitcnt vmcnt(4)" ::: "memory")
#define LGKM8() asm volatile("s_waitcnt lgkmcnt(8)" ::: "memory")
#define LGKM0() asm volatile("s_waitcnt lgkmcnt(0)" ::: "memory")
#define SCHB()  __builtin_amdgcn_sched_barrier(0)
#define SBAR()  __builtin_amdgcn_s_barrier()

// ---------------------------------------------------------------------------
// R20 GEMM1: split fp16 8-phase port of the R19-verified gemm_p8 skeleton.
// 256x256, BK=32, 8 waves (2Mx4N). Buffer = {Ahi 16KB, Alo 16KB, B 16KB},
// dbuf 96KB. 2 K-tiles per iteration (buf0 phases 0-3, buf1 phases 4-7).
// Phase p computes quadrant rows {2p,2p+1}: 16 MFMA = (ah + al) x b[4].
// Per phase: frag ds_reads -> 2 staging loads -> s_barrier -> lgkmcnt(0)+
// sched_barrier -> setprio(1) MFMA setprio(0) -> [counted vmcnt] -> s_barrier.
// Stage plan / FIFO (mirrors gemm_p8): ph0: buf1.Ahi(T1); ph1: buf1.Alo(T1);
// ph2: buf0'.B(T2); ph4: buf0'.Ahi(T2); ph5: buf0'.Alo(T2); ph6: buf1'.B(T3).
// vmcnt(2)@ph3 retires buf1's 6 loads (B from prev ph6, A from ph0-1),
// keeps buf0'.B in flight; vmcnt(2)@ph7 retires buf0''s 6. Never 0 mid-loop.
// Region lifetimes: B read only at FIRST phase -> free from ph2/ph6; A
// regions free after their tile's last phase. Prologue {buf0.B/Ahi/Alo,
// buf1.B; vmcnt(2)} reproduces steady state. Tail: no stages, vmcnt(0)@ph3.
// Swizzle (R13/R15-verified 0-conflict): slot_phys = slot_log^((row>>1)&3)
// on pre-swizzled global source AND frag ds_read offsets.
// Epilogue: +bias, fp16 store (keys).
// ---------------------------------------------------------------------------
__launch_bounds__(512, 2)
__global__ void gemm1_p8(const u16* __restrict__ Ahi, const u16* __restrict__ Alo,
                         const u16* __restrict__ Bm,
                         const float* __restrict__ bias, u16* __restrict__ Ch,
                         int N, int gn, int gmn)
{
    constexpr int O_AL  = 8192;
    constexpr int O_B   = 16384;
    constexpr int BUFSZ = 24576;                 // u16 per buffer (48KB)
    __shared__ __align__(16) u16 lds[2 * BUFSZ]; // 96KB

    const int tid  = threadIdx.x;
    const int lane = tid & 63;
    const int wv   = tid >> 6;
    const int wr   = wv >> 2, wc = wv & 3;

    const int d   = blockIdx.x;
    const int cpx = gridDim.x >> 3;
    const int swz = (d & 7) * cpx + (d >> 3);
    const long long z = swz / gmn;               // 0 here (gmn=grid)
    const int r_  = swz % gmn;
    const int bm  = (r_ / gn) * 256;
    const int bn  = (r_ % gn) * 256;

    const char* pAh = (const char*)Ahi;
    const char* pAl = (const char*)Alo;
    const char* pB  = (const char*)Bm;

    // staging geometry (R15 BK32 verified): chunk c: row=c>>2, phys slot=c&3,
    // src slot=(c&3)^((row>>1)&3); thread t stages chunks {t, t+512}.
    const int r0 = tid >> 2;
    const int xc = (tid & 3) ^ ((r0 >> 1) & 3);
    const long long aof = (long long)(bm + r0) * 2048 + xc * 16;
    const long long bof = (long long)(bn + r0) * 2048 + xc * 16;
    const long long ao2 = aof + 128 * 2048;
    const long long bo2 = bof + 128 * 2048;
    const int d0 = tid * 8;
    const int d1 = d0 + 4096;

    int offA[8], offB[4];
#pragma unroll
    for (int i = 0; i < 8; ++i) {
        const int r = wr * 128 + i * 16 + (lane & 15);
        offA[i] = r * 32 + ((((lane >> 4) ^ (r >> 1)) & 3) << 3);
    }
#pragma unroll
    for (int j = 0; j < 4; ++j) {
        const int r = wc * 64 + j * 16 + (lane & 15);
        offB[j] = O_B + r * 32 + ((((lane >> 4) ^ (r >> 1)) & 3) << 3);
    }

    f32x4 acc[8][4];
#pragma unroll
    for (int i = 0; i < 8; ++i)
#pragma unroll
        for (int j = 0; j < 4; ++j)
            acc[i][j] = (f32x4){0.f, 0.f, 0.f, 0.f};

    f16x8 bb[4];      // B frags of the current K-tile (live 4 phases)

#define SAH(NB, KB) do { load_lds16((const u16*)(pAh + aof + (KB)), lds + (NB) + d0);          \
                         load_lds16((const u16*)(pAh + ao2 + (KB)), lds + (NB) + d1); } while (0)
#define SAL(NB, KB) do { load_lds16((const u16*)(pAl + aof + (KB)), lds + (NB) + O_AL + d0);   \
                         load_lds16((const u16*)(pAl + ao2 + (KB)), lds + (NB) + O_AL + d1); } while (0)
#define SB_(NB, KB) do { load_lds16((const u16*)(pB + bof + (KB)), lds + (NB) + O_B + d0);     \
                         load_lds16((const u16*)(pB + bo2 + (KB)), lds + (NB) + O_B + d1); } while (0)
#define RD_BB(CB) do {                                                        \
        _Pragma("unroll")                                                     \
        for (int j = 0; j < 4; ++j)                                           \
            bb[j] = *(const f16x8*)(lds + (CB) + offB[j]);                    \
    } while (0)
#define PHASE(CB, I0, FIRST, STAGES, WAITST) do {                             \
        if (FIRST) RD_BB(CB);                                                 \
        f16x8 ah0 = *(const f16x8*)(lds + (CB) + offA[(I0)]);                 \
        f16x8 ah1 = *(const f16x8*)(lds + (CB) + offA[(I0) + 1]);             \
        f16x8 al0 = *(const f16x8*)(lds + (CB) + O_AL + offA[(I0)]);          \
        f16x8 al1 = *(const f16x8*)(lds + (CB) + O_AL + offA[(I0) + 1]);      \
        STAGES;                                                               \
        SBAR();                                                               \
        LGKM0(); SCHB();                                                      \
        __builtin_amdgcn_s_setprio(1);                                        \
        _Pragma("unroll")                                                     \
        for (int j = 0; j < 4; ++j) {                                         \
            acc[(I0)][j]     = MFMA_F16(ah0, bb[j], acc[(I0)][j]);            \
            acc[(I0)][j]     = MFMA_F16(al0, bb[j], acc[(I0)][j]);            \
            acc[(I0) + 1][j] = MFMA_F16(ah1, bb[j], acc[(I0) + 1][j]);        \
            acc[(I0) + 1][j] = MFMA_F16(al1, bb[j], acc[(I0) + 1][j]);        \
        }                                                                     \
        __builtin_amdgcn_s_setprio(0);                                        \
        WAITST;                                                               \
        SBAR();                                                               \
    } while (0)

    constexpr int NT2 = 16;      // iterations; 2 K-tiles (BK=32) each

    // prologue: buf0 = T0 (B, Ahi, Alo), buf1.B = T1; vmcnt(2) keeps T1.B.
    SB_(0, 0); SAH(0, 0); SAL(0, 0);
    SB_(BUFSZ, 64);
    VMW2();
    SBAR();

    for (int it = 0; it < NT2; ++it) {
        const long long kb1 = (long long)(2 * it + 1) * 64;
        const long long kb2 = (long long)(2 * it + 2) * 64;
        const long long kb3 = (long long)(2 * it + 3) * 64;
        const bool st2 = (it + 1) < NT2;

        // ---- buf0 (tile 2it), phases 0..3
        PHASE(0, 0, true,  { SAH(BUFSZ, kb1); }, );
        PHASE(0, 2, false, { SAL(BUFSZ, kb1); }, );
        PHASE(0, 4, false, { if (st2) SB_(0, kb2); }, );
        PHASE(0, 6, false, { },
              { if (st2) { VMW2(); } else { VMW0(); } });
        // ---- buf1 (tile 2it+1), phases 4..7
        PHASE(BUFSZ, 0, true,  { if (st2) SAH(0, kb2); }, );
        PHASE(BUFSZ, 2, false, { if (st2) SAL(0, kb2); }, );
        PHASE(BUFSZ, 4, false, { if (st2) SB_(BUFSZ, kb3); }, );
        PHASE(BUFSZ, 6, false, { },
              { if (st2) VMW2(); });
    }
#undef SAH
#undef SAL
#undef SB_
#undef RD_BB
#undef PHASE

    // epilogue; C/D map: col = lane&15, row = (lane>>4)*4 + e  [m89/m91]
    (void)z;
#pragma unroll
    for (int i = 0; i < 8; ++i) {
        const int row0 = bm + wr * 128 + i * 16 + ((lane >> 4) << 2);
#pragma unroll
        for (int j = 0; j < 4; ++j) {
            const int col = bn + wc * 64 + j * 16 + (lane & 15);
#pragma unroll
            for (int e = 0; e < 4; ++e) {
                const long long idx = (long long)(row0 + e) * N + col;
                Ch[idx] = f2h(acc[i][j][e] + bias[col]);
            }
        }
    }
}

// ---------------------------------------------------------------------------
// R19 dense GEMM (verified): faithful m201 8-phase, 256x256, BK=64, dbuf
// 128KB, 2 K-tiles/iteration, counted vmcnt(4) at ph3/ph7. ~64us/dispatch.
// ---------------------------------------------------------------------------
template<int EPI>
__launch_bounds__(512, 2)
__global__ void gemm_p8(const u16* __restrict__ Am, const u16* __restrict__ Bm,
                        float* __restrict__ Cf,
                        int N, int gn, int gmn,
                        long long sA, long long sB, long long sC)
{
    constexpr int OB    = 16384;
    constexpr int BUFSZ = 32768;
    __shared__ __align__(16) u16 lds[2 * BUFSZ];

    const int tid  = threadIdx.x;
    const int lane = tid & 63;
    const int wv   = tid >> 6;
    const int wr   = wv >> 2, wc = wv & 3;

    const int d   = blockIdx.x;
    const int cpx = gridDim.x >> 3;
    const int swz = (d & 7) * cpx + (d >> 3);
    const long long z = swz / gmn;
    const int r_  = swz % gmn;
    const int bm  = (r_ / gn) * 256;
    const int bn  = (r_ % gn) * 256;

    const char* pA = (const char*)(Am + z * sA);
    const char* pB = (const char*)(Bm + z * sB);

    const int rr  = tid >> 3;
    const int xcv = (tid & 7) ^ (rr & 7);
    long long aofs[4], bofs[4];
#pragma unroll
    for (int j = 0; j < 4; ++j) {
        aofs[j] = (long long)(bm + rr + j * 64) * 2048 + xcv * 16;
        bofs[j] = (long long)(bn + rr + j * 64) * 2048 + xcv * 16;
    }

    int offA[8][2], offB[4][2];
#pragma unroll
    for (int i = 0; i < 8; ++i) {
        const int r = wr * 128 + i * 16 + (lane & 15);
#pragma unroll
        for (int s = 0; s < 2; ++s)
            offA[i][s] = r * 64 + ((((s * 4 + (lane >> 4)) ^ r) & 7) << 3);
    }
#pragma unroll
    for (int j = 0; j < 4; ++j) {
        const int r = wc * 64 + j * 16 + (lane & 15);
#pragma unroll
        for (int s = 0; s < 2; ++s)
            offB[j][s] = OB + r * 64 + ((((s * 4 + (lane >> 4)) ^ r) & 7) << 3);
    }

    f32x4 acc[8][4];
#pragma unroll
    for (int i = 0; i < 8; ++i)
#pragma unroll
        for (int j = 0; j < 4; ++j)
            acc[i][j] = (f32x4){0.f, 0.f, 0.f, 0.f};

    f16x8 bb[4][2];

#define STA(NB, J, KB) load_lds16((const u16*)(pA + aofs[J] + (KB)), \
                                  lds + (NB) + tid * 8 + (J) * 4096)
#define STB(NB, J, KB) load_lds16((const u16*)(pB + bofs[J] + (KB)), \
                                  lds + (NB) + OB + tid * 8 + (J) * 4096)
#define RD_BB(CB) do {                                                        \
        _Pragma("unroll")                                                     \
        for (int j = 0; j < 4; ++j) {                                         \
            bb[j][0] = *(const f16x8*)(lds + (CB) + offB[j][0]);              \
            bb[j][1] = *(const f16x8*)(lds + (CB) + offB[j][1]);              \
        }                                                                     \
    } while (0)
#define PHASE(CB, I0, FIRST, STAGES, WAITST) do {                             \
        if (FIRST) RD_BB(CB);                                                 \
        f16x8 a00 = *(const f16x8*)(lds + (CB) + offA[(I0)][0]);              \
        f16x8 a01 = *(const f16x8*)(lds + (CB) + offA[(I0)][1]);              \
        f16x8 a10 = *(const f16x8*)(lds + (CB) + offA[(I0) + 1][0]);          \
        f16x8 a11 = *(const f16x8*)(lds + (CB) + offA[(I0) + 1][1]);          \
        STAGES;                                                               \
        if (FIRST) LGKM8();                                                   \
        SBAR();                                                               \
        LGKM0(); SCHB();                                                      \
        __builtin_amdgcn_s_setprio(1);                                        \
        _Pragma("unroll")                                                     \
        for (int j = 0; j < 4; ++j) {                                         \
            acc[(I0)][j]     = MFMA_F16(a00, bb[j][0], acc[(I0)][j]);         \
            acc[(I0)][j]     = MFMA_F16(a01, bb[j][1], acc[(I0)][j]);         \
            acc[(I0) + 1][j] = MFMA_F16(a10, bb[j][0], acc[(I0) + 1][j]);     \
            acc[(I0) + 1][j] = MFMA_F16(a11, bb[j][1], acc[(I0) + 1][j]);     \
        }                                                                     \
        __builtin_amdgcn_s_setprio(0);                                        \
        WAITST;                                                               \
        SBAR();                                                               \
    } while (0)

    constexpr int NT2 = 8;

    STB(0, 0, 0); STB(0, 1, 0); STB(0, 2, 0); STB(0, 3, 0);
    STA(0, 0, 0); STA(0, 1, 0); STA(0, 2, 0); STA(0, 3, 0);
    STB(BUFSZ, 0, 128); STB(BUFSZ, 1, 128); STB(BUFSZ, 2, 128); STB(BUFSZ, 3, 128);
    VMW4();
    SBAR();

    for (int it = 0; it < NT2; ++it) {
        const long long kb1 = (long long)(2 * it + 1) * 128;
        const long long kb2 = (long long)(2 * it + 2) * 128;
        const long long kb3 = (long long)(2 * it + 3) * 128;
        const bool st2 = (it + 1) < NT2;

        PHASE(0, 0, true,  { STA(BUFSZ, 0, kb1); STA(BUFSZ, 1, kb1); }, );
        PHASE(0, 2, false, { STA(BUFSZ, 2, kb1); STA(BUFSZ, 3, kb1); }, );
        PHASE(0, 4, false, { if (st2) { STB(0, 0, kb2); STB(0, 1, kb2); } }, );
        PHASE(0, 6, false, { if (st2) { STB(0, 2, kb2); STB(0, 3, kb2); } },
              { if (st2) { VMW4(); } else { VMW0(); } });
        PHASE(BUFSZ, 0, true,  { if (st2) { STA(0, 0, kb2); STA(0, 1, kb2); } }, );
        PHASE(BUFSZ, 2, false, { if (st2) { STA(0, 2, kb2); STA(0, 3, kb2); } }, );
        PHASE(BUFSZ, 4, false, { if (st2) { STB(BUFSZ, 0, kb3); STB(BUFSZ, 1, kb3); } }, );
        PHASE(BUFSZ, 6, false, { if (st2) { STB(BUFSZ, 2, kb3); STB(BUFSZ, 3, kb3); } },
              { if (st2) VMW4(); });
    }
#undef STA
#undef STB
#undef RD_BB
#undef PHASE

    const long long Cbase = z * sC;
#pragma unroll
    for (int i = 0; i < 8; ++i) {
        const int row0 = bm + wr * 128 + i * 16 + ((lane >> 4) << 2);
#pragma unroll
        for (int j = 0; j < 4; ++j) {
            const int col = bn + wc * 64 + j * 16 + (lane & 15);
#pragma unroll
            for (int e = 0; e < 4; ++e) {
                const float v = acc[i][j][e];
                const long long idx = Cbase + (long long)(row0 + e) * N + col;
                if constexpr (EPI == 0) Cf[idx] = v;
                else                    Cf[idx] = fmaxf(v, 0.f);
            }
        }
    }
}

// fp32 -> fp16 single, 4 elems/thread (p pre-pass)
__global__ void cvt_f16(const float* __restrict__ in, u16* __restrict__ o16,
                        long long n4)
{
    const long long i = (long long)blockIdx.x * 256 + threadIdx.x;
    if (i >= n4) return;
    const float4 v = ((const float4*)in)[i];
    ushort4 h;
    h.x = f2h(v.x); h.y = f2h(v.y); h.z = f2h(v.z); h.w = f2h(v.w);
    ((ushort4*)o16)[i] = h;
}

// fused q pre-pass: q_hi, q_lo (straight, fp16) and qT (transposed, fp16)
__global__ void fuse_cvt_q(const float* __restrict__ q, u16* __restrict__ hi,
                           u16* __restrict__ lo, u16* __restrict__ thi)
{
    __shared__ float t[32][33];
    const long long z = blockIdx.z;
    const long long base = z * 1048576;
    const int r0 = blockIdx.y * 32, c0 = blockIdx.x * 32;
    for (int j = threadIdx.y; j < 32; j += 8) {
        const float v = q[base + (long long)(r0 + j) * 1024 + c0 + threadIdx.x];
        t[j][threadIdx.x] = v;
        const long long o = base + (long long)(r0 + j) * 1024 + c0 + threadIdx.x;
        const u16 h = f2h(v);
        hi[o] = h;
        lo[o] = f2h(v - h2f(h));
    }
    __syncthreads();
    for (int j = threadIdx.y; j < 32; j += 8)
        thi[base + (long long)(c0 + j) * 1024 + r0 + threadIdx.x] = f2h(t[threadIdx.x][j]);
}

// Wt[c][r] = W[r][c], fp16 single
__global__ void transpose_cvt_w(const float* __restrict__ in, u16* __restrict__ hi)
{
    __shared__ float t[32][33];
    const int r0 = blockIdx.y * 32, c0 = blockIdx.x * 32;
    for (int j = threadIdx.y; j < 32; j += 8)
        t[j][threadIdx.x] = in[(long long)(r0 + j) * 1024 + c0 + threadIdx.x];
    __syncthreads();
    for (int j = threadIdx.y; j < 32; j += 8)
        hi[(long long)(c0 + j) * 1024 + r0 + threadIdx.x] = f2h(t[threadIdx.x][j]);
}

// row softmax (fp32 in, fp16 out)
__global__ void softmax_f16(const float* __restrict__ S, u16* __restrict__ A)
{
    const long long row = blockIdx.x;
    const float* r = S + row * (long long)LQ_N;
    const int t = threadIdx.x;
    float4 v = ((const float4*)r)[t];

    float m = fmaxf(fmaxf(v.x, v.y), fmaxf(v.z, v.w));
#pragma unroll
    for (int off = 32; off > 0; off >>= 1)
        m = fmaxf(m, __shfl_xor(m, off));

    __shared__ float red[4];
    const int lane = t & 63, wid = t >> 6;
    if (lane == 0) red[wid] = m;
    __syncthreads();
    m = fmaxf(fmaxf(red[0], red[1]), fmaxf(red[2], red[3]));
    __syncthreads();

    v.x = __expf(v.x - m); v.y = __expf(v.y - m);
    v.z = __expf(v.z - m); v.w = __expf(v.w - m);
    float s = v.x + v.y + v.z + v.w;
#pragma unroll
    for (int off = 32; off > 0; off >>= 1)
        s += __shfl_xor(s, off);
    if (lane == 0) red[wid] = s;
    __syncthreads();
    s = red[0] + red[1] + red[2] + red[3];

    const float inv = 1.0f / s;
    ushort4 o;
    o.x = f2h(v.x * inv); o.y = f2h(v.y * inv);
    o.z = f2h(v.z * inv); o.w = f2h(v.w * inv);
    ((ushort4*)(A + row * (long long)LQ_N))[t] = o;
}

// ---------------------------------------------------------------------------
// Fallback fp32 path (round-1, verified; needs only 128 MB ws)
// ---------------------------------------------------------------------------
#define BM 128
#define BN 128
#define BK 8
#define TM 8
#define TN 8

template<bool TRANSB, bool BIAS, bool RELU>
__launch_bounds__(256)
__global__ void gemm_k(const float* __restrict__ A, const float* __restrict__ Bmat,
                       const float* __restrict__ bias, float* __restrict__ C,
                       int M, int N, int K,
                       long long sA, long long sB, long long sC)
{
    __shared__ float As[BK][BM];
    __shared__ float Bs[BK][BN];
    const int tid = threadIdx.x;
    const int tx = tid & 15;
    const int ty = tid >> 4;
    const int bn = blockIdx.x * BN;
    const int bm = blockIdx.y * BM;
    const long long z = blockIdx.z;
    A += z * sA; Bmat += z * sB; C += z * sC;
    float acc[TM][TN];
#pragma unroll
    for (int i = 0; i < TM; i++)
#pragma unroll
        for (int j = 0; j < TN; j++) acc[i][j] = 0.f;
    const int arow = tid >> 1;
    const int acol = (tid & 1) * 4;
    const int bk_n = tid >> 5;
    const int bn_n = (tid & 31) * 4;
    for (int k0 = 0; k0 < K; k0 += BK) {
        float4 a4 = *(const float4*)&A[(long long)(bm + arow) * K + k0 + acol];
        As[acol + 0][arow] = a4.x; As[acol + 1][arow] = a4.y;
        As[acol + 2][arow] = a4.z; As[acol + 3][arow] = a4.w;
        if (TRANSB) {
            float4 b4 = *(const float4*)&Bmat[(long long)(bn + arow) * K + k0 + acol];
            Bs[acol + 0][arow] = b4.x; Bs[acol + 1][arow] = b4.y;
            Bs[acol + 2][arow] = b4.z; Bs[acol + 3][arow] = b4.w;
        } else {
            float4 b4 = *(const float4*)&Bmat[(long long)(k0 + bk_n) * N + bn + bn_n];
            *(float4*)&Bs[bk_n][bn_n] = b4;
        }
        __syncthreads();
#pragma unroll
        for (int k = 0; k < BK; k++) {
            float a[TM], b[TN];
            *(float4*)&a[0] = *(const float4*)&As[k][ty * TM];
            *(float4*)&a[4] = *(const float4*)&As[k][ty * TM + 4];
            *(float4*)&b[0] = *(const float4*)&Bs[k][tx * TN];
            *(float4*)&b[4] = *(const float4*)&Bs[k][tx * TN + 4];
#pragma unroll
            for (int i = 0; i < TM; i++)
#pragma unroll
                for (int j = 0; j < TN; j++)
                    acc[i][j] = fmaf(a[i], b[j], acc[i][j]);
        }
        __syncthreads();
    }
#pragma unroll
    for (int i = 0; i < TM; i++) {
        const int row = bm + ty * TM + i;
#pragma unroll
        for (int j = 0; j < TN; j += 4) {
            const int col = bn + tx * TN + j;
            float4 v;
            v.x = acc[i][j + 0]; v.y = acc[i][j + 1];
            v.z = acc[i][j + 2]; v.w = acc[i][j + 3];
            if (BIAS) {
                v.x += bias[col + 0]; v.y += bias[col + 1];
                v.z += bias[col + 2]; v.w += bias[col + 3];
            }
            if (RELU) {
                v.x = fmaxf(v.x, 0.f); v.y = fmaxf(v.y, 0.f);
                v.z = fmaxf(v.z, 0.f); v.w = fmaxf(v.w, 0.f);
            }
            *(float4*)&C[(long long)row * N + col] = v;
        }
    }
}

__global__ void softmax_k(float* __restrict__ S)
{
    const long long row = blockIdx.x;
    float* r = S + row * (long long)LQ_N;
    const int t = threadIdx.x;
    float4 v = ((float4*)r)[t];
    float m = fmaxf(fmaxf(v.x, v.y), fmaxf(v.z, v.w));
#pragma unroll
    for (int off = 32; off > 0; off >>= 1)
        m = fmaxf(m, __shfl_xor(m, off));
    __shared__ float red[4];
    const int lane = t & 63, wid = t >> 6;
    if (lane == 0) red[wid] = m;
    __syncthreads();
    m = fmaxf(fmaxf(red[0], red[1]), fmaxf(red[2], red[3]));
    __syncthreads();
    v.x = __expf(v.x - m); v.y = __expf(v.y - m);
    v.z = __expf(v.z - m); v.w = __expf(v.w - m);
    float s = v.x + v.y + v.z + v.w;
#pragma unroll
    for (int off = 32; off > 0; off >>= 1)
        s += __shfl_xor(s, off);
    if (lane == 0) red[wid] = s;
    __syncthreads();
    s = red[0] + red[1] + red[2] + red[3];
    const float inv = 1.0f / s;
    v.x *= inv; v.y *= inv; v.z *= inv; v.w *= inv;
    ((float4*)r)[t] = v;
}

extern "C" void kernel_launch(void* const* d_in, const int* in_sizes, int n_in,
                              void* d_out, int out_size, void* d_ws, size_t ws_size,
                              hipStream_t stream)
{
    const float* p    = (const float*)d_in[0];
    const float* q    = (const float*)d_in[1];
    const float* W    = (const float*)d_in[2];
    const float* bias = (const float*)d_in[3];
    float* out = (float*)d_out;

    const size_t MB32 = 33554432ull;                 // 32 MB unit
    const size_t NEED = 5 * MB32 + 2097152ull;       // 162 MB

    if (ws_size >= NEED) {
        char* w = (char*)d_ws;
        u16* p16   = (u16*)(w + 0 * MB32);
        u16* q_hi  = (u16*)(w + 1 * MB32);
        u16* q_lo  = (u16*)(w + 2 * MB32);
        u16* keys  = (u16*)(w + 3 * MB32);
        u16* qT    = (u16*)(w + 4 * MB32);
        u16* Wt    = (u16*)(w + 5 * MB32);
        float* scores = (float*)(w + 1 * MB32);  // reuses q_hi/q_lo after GEMM1
        u16* attn     = (u16*)(w + 0 * MB32);    // reuses p16 after GEMM2

        const long long n4 = (long long)B_N * LQ_N * H_N / 4;
        cvt_f16<<<dim3((unsigned)(n4 / 256)), 256, 0, stream>>>(p, p16, n4);
        fuse_cvt_q<<<dim3(32, 32, B_N), dim3(32, 8), 0, stream>>>(q, q_hi, q_lo, qT);
        transpose_cvt_w<<<dim3(32, 32, 1), dim3(32, 8), 0, stream>>>(W, Wt);

        // keys = (q_hi + q_lo) @ Wt + b : 8-phase split (R20 port).
        gemm1_p8<<<256, 512, 0, stream>>>(
            q_hi, q_lo, Wt, bias, keys,
            H_N, /*gn=*/4, /*gmn=*/256);

        // scores[b] = p16[b] @ keys[b]^T : 8-phase dense (R19-verified).
        gemm_p8<0><<<256, 512, 0, stream>>>(
            p16, keys, scores,
            LQ_N, /*gn=*/4, /*gmn=*/16,
            (long long)LP_N * H_N, (long long)LQ_N * H_N, (long long)LP_N * LQ_N);

        softmax_f16<<<B_N * LP_N, 256, 0, stream>>>(scores, attn);

        // out[b] = relu(attn[b] @ q[b]) : 8-phase dense (R19-verified).
        gemm_p8<2><<<256, 512, 0, stream>>>(
            attn, qT, out,
            H_N, /*gn=*/4, /*gmn=*/16,
            (long long)LP_N * LQ_N, (long long)H_N * LQ_N, (long long)LP_N * H_N);
    } else {
        float* keys   = (float*)d_ws;
        float* scores = keys + (long long)B_N * LQ_N * H_N;

        gemm_k<false, true, false><<<dim3(H_N / BN, (B_N * LQ_N) / BM, 1), 256, 0, stream>>>(
            q, W, bias, keys, B_N * LQ_N, H_N, H_N, 0, 0, 0);
        gemm_k<true, false, false><<<dim3(LQ_N / BN, LP_N / BM, B_N), 256, 0, stream>>>(
            p, keys, nullptr, scores, LP_N, LQ_N, H_N,
            (long long)LP_N * H_N, (long long)LQ_N * H_N, (long long)LP_N * LQ_N);
        softmax_k<<<B_N * LP_N, 256, 0, stream>>>(scores);
        gemm_k<false, false, true><<<dim3(H_N / BN, LP_N / BM, B_N), 256, 0, stream>>>(
            scores, q, nullptr, out, LP_N, H_N, LQ_N,
            (long long)LP_N * LQ_N, (long long)LQ_N * H_N, (long long)LP_N * H_N);
    }
}

// Round 22
// 217.456 us; speedup vs baseline: 1.0225x; 1.0225x over previous
//
#include <hip/hip_runtime.h>
#include <hip/hip_bf16.h>

#define B_N 16
#define LP_N 1024
#define LQ_N 1024
#define H_N 1024

typedef unsigned short u16;
typedef __attribute__((ext_vector_type(8))) _Float16 f16x8;
typedef __attribute__((ext_vector_type(4))) float f32x4;

__device__ __forceinline__ u16 f2h(float x) {
    _Float16 h = (_Float16)x;
    return *(u16*)&h;
}
__device__ __forceinline__ float h2f(u16 u) {
    _Float16 h;
    *(u16*)&h = u;
    return (float)h;
}

__device__ __forceinline__ void load_lds16(const u16* g, u16* l) {
    __builtin_amdgcn_global_load_lds(
        (const __attribute__((address_space(1))) void*)g,
        (__attribute__((address_space(3))) void*)l, 16, 0, 0);
}

#define MFMA_F16(a, b, c) __builtin_amdgcn_mfma_f32_16x16x32_f16(a, b, c, 0, 0, 0)
#define VMW0()  asm volatile("s_waitcnt vmcnt(0)" ::: "memory")
#define VMW4()  asm volatile("s_waitcnt vmcnt(4)" ::: "memory")
#define LGKM8() asm volatile("s_waitcnt lgkmcnt(8)" ::: "memory")
#define LGKM0() asm volatile("s_waitcnt lgkmcnt(0)" ::: "memory")
#define SCHB()  __builtin_amdgcn_sched_barrier(0)
#define SBAR()  __builtin_amdgcn_s_barrier()

// ---------------------------------------------------------------------------
// GEMM1 (R15/R19-verified config): 256x256 fp16 split, BK=32, dbuf, per-tile
// vmcnt(0)+s_barrier gate. R20 showed the 8-phase port is NOT better here.
// ---------------------------------------------------------------------------
template<bool SPLIT, int EPI>
__launch_bounds__(512, 2)
__global__ void gemm2t(const u16* __restrict__ Ahi, const u16* __restrict__ Alo,
                       const u16* __restrict__ Bm,
                       const float* __restrict__ bias,
                       float* __restrict__ Cf, u16* __restrict__ Ch,
                       int N, int gn, int gmn,
                       long long sA, long long sB, long long sC)
{
    constexpr int REG  = 8192;
    constexpr int O_AL = REG;
    constexpr int O_B  = SPLIT ? 2 * REG : REG;
    constexpr int BUF  = SPLIT ? 3 * REG : 2 * REG;
    __shared__ __align__(16) u16 lds[2 * BUF];

    const int tid  = threadIdx.x;
    const int lane = tid & 63;
    const int wv   = tid >> 6;
    const int wr   = wv >> 2, wc = wv & 3;

    const int d   = blockIdx.x;
    const int cpx = gridDim.x >> 3;
    const int swz = (d & 7) * cpx + (d >> 3);
    const long long z = swz / gmn;
    const int r_  = swz % gmn;
    const int bm  = (r_ / gn) * 256;
    const int bn  = (r_ % gn) * 256;

    const char* pAh = (const char*)(Ahi + z * sA);
    const char* pAl = (const char*)(Alo + z * sA);
    const char* pB  = (const char*)(Bm + z * sB);

    const int r0 = tid >> 2;
    const int xc = (tid & 3) ^ ((r0 >> 1) & 3);
    const long long aof = (long long)(bm + r0) * 2048 + xc * 16;
    const long long bof = (long long)(bn + r0) * 2048 + xc * 16;
    const long long ao2 = aof + 128 * 2048;
    const long long bo2 = bof + 128 * 2048;
    const int d0 = tid * 8;
    const int d1 = d0 + 4096;

    int offA[8], offB[4];
#pragma unroll
    for (int i = 0; i < 8; ++i) {
        const int r = wr * 128 + i * 16 + (lane & 15);
        offA[i] = r * 32 + ((((lane >> 4) ^ (r >> 1)) & 3) << 3);
    }
#pragma unroll
    for (int j = 0; j < 4; ++j) {
        const int r = wc * 64 + j * 16 + (lane & 15);
        offB[j] = r * 32 + ((((lane >> 4) ^ (r >> 1)) & 3) << 3);
    }

    f32x4 acc[8][4];
#pragma unroll
    for (int i = 0; i < 8; ++i)
#pragma unroll
        for (int j = 0; j < 4; ++j)
            acc[i][j] = (f32x4){0.f, 0.f, 0.f, 0.f};

#define STG(NB, KB) do {                                                      \
        load_lds16((const u16*)(pAh + aof + (KB)), lds + (NB) + d0);          \
        load_lds16((const u16*)(pAh + ao2 + (KB)), lds + (NB) + d1);          \
        load_lds16((const u16*)(pB + bof + (KB)), lds + (NB) + O_B + d0);     \
        load_lds16((const u16*)(pB + bo2 + (KB)), lds + (NB) + O_B + d1);     \
        if constexpr (SPLIT) {                                                \
            load_lds16((const u16*)(pAl + aof + (KB)), lds + (NB) + O_AL + d0); \
            load_lds16((const u16*)(pAl + ao2 + (KB)), lds + (NB) + O_AL + d1); \
        }                                                                     \
    } while (0)

#define TERM(AF, BF) do {                                                     \
        __builtin_amdgcn_s_setprio(1);                                        \
        _Pragma("unroll")                                                     \
        for (int i = 0; i < 8; ++i)                                           \
            _Pragma("unroll")                                                 \
            for (int j = 0; j < 4; ++j)                                       \
                acc[i][j] = MFMA_F16(AF[i], BF[j], acc[i][j]);                \
        __builtin_amdgcn_s_setprio(0);                                        \
    } while (0)

    constexpr int NT = 32;

    STG(0, 0);

    for (int t = 0; t < NT; ++t) {
        const int cb = (t & 1) ? BUF : 0;
        const int nb = (t & 1) ? 0 : BUF;
        const long long kb = (long long)(t + 1) * 64;

        VMW0();
        SBAR();
        f16x8 b[4], ah[8], al[8];
#pragma unroll
        for (int j = 0; j < 4; ++j)
            b[j] = *(const f16x8*)(lds + cb + O_B + offB[j]);
#pragma unroll
        for (int i = 0; i < 8; ++i)
            ah[i] = *(const f16x8*)(lds + cb + offA[i]);
        if constexpr (SPLIT) {
#pragma unroll
            for (int i = 0; i < 8; ++i)
                al[i] = *(const f16x8*)(lds + cb + O_AL + offA[i]);
        }
        if (t + 1 < NT) STG(nb, kb);
        if constexpr (SPLIT) { LGKM8(); } else { LGKM0(); }
        SCHB();
        TERM(ah, b);
        if constexpr (SPLIT) {
            LGKM0(); SCHB();
            TERM(al, b);
        }
    }
#undef STG
#undef TERM

    const long long Cbase = z * sC;
#pragma unroll
    for (int i = 0; i < 8; ++i) {
        const int row0 = bm + wr * 128 + i * 16 + ((lane >> 4) << 2);
#pragma unroll
        for (int j = 0; j < 4; ++j) {
            const int col = bn + wc * 64 + j * 16 + (lane & 15);
#pragma unroll
            for (int e = 0; e < 4; ++e) {
                const float v = acc[i][j][e];
                const long long idx = Cbase + (long long)(row0 + e) * N + col;
                if constexpr (EPI == 0) {
                    Cf[idx] = v;
                } else if constexpr (EPI == 1) {
                    Ch[idx] = f2h(v + bias[col]);
                } else {
                    Cf[idx] = fmaxf(v, 0.f);
                }
            }
        }
    }
}

// ---------------------------------------------------------------------------
// R19 dense GEMM (verified): faithful m201 8-phase, 256x256, BK=64, dbuf
// 128KB, 2 K-tiles/iteration, counted vmcnt(4) at ph3/ph7. ~64us/dispatch.
// ---------------------------------------------------------------------------
template<int EPI>
__launch_bounds__(512, 2)
__global__ void gemm_p8(const u16* __restrict__ Am, const u16* __restrict__ Bm,
                        float* __restrict__ Cf,
                        int N, int gn, int gmn,
                        long long sA, long long sB, long long sC)
{
    constexpr int OB    = 16384;
    constexpr int BUFSZ = 32768;
    __shared__ __align__(16) u16 lds[2 * BUFSZ];

    const int tid  = threadIdx.x;
    const int lane = tid & 63;
    const int wv   = tid >> 6;
    const int wr   = wv >> 2, wc = wv & 3;

    const int d   = blockIdx.x;
    const int cpx = gridDim.x >> 3;
    const int swz = (d & 7) * cpx + (d >> 3);
    const long long z = swz / gmn;
    const int r_  = swz % gmn;
    const int bm  = (r_ / gn) * 256;
    const int bn  = (r_ % gn) * 256;

    const char* pA = (const char*)(Am + z * sA);
    const char* pB = (const char*)(Bm + z * sB);

    const int rr  = tid >> 3;
    const int xcv = (tid & 7) ^ (rr & 7);
    long long aofs[4], bofs[4];
#pragma unroll
    for (int j = 0; j < 4; ++j) {
        aofs[j] = (long long)(bm + rr + j * 64) * 2048 + xcv * 16;
        bofs[j] = (long long)(bn + rr + j * 64) * 2048 + xcv * 16;
    }

    int offA[8][2], offB[4][2];
#pragma unroll
    for (int i = 0; i < 8; ++i) {
        const int r = wr * 128 + i * 16 + (lane & 15);
#pragma unroll
        for (int s = 0; s < 2; ++s)
            offA[i][s] = r * 64 + ((((s * 4 + (lane >> 4)) ^ r) & 7) << 3);
    }
#pragma unroll
    for (int j = 0; j < 4; ++j) {
        const int r = wc * 64 + j * 16 + (lane & 15);
#pragma unroll
        for (int s = 0; s < 2; ++s)
            offB[j][s] = OB + r * 64 + ((((s * 4 + (lane >> 4)) ^ r) & 7) << 3);
    }

    f32x4 acc[8][4];
#pragma unroll
    for (int i = 0; i < 8; ++i)
#pragma unroll
        for (int j = 0; j < 4; ++j)
            acc[i][j] = (f32x4){0.f, 0.f, 0.f, 0.f};

    f16x8 bb[4][2];

#define STA(NB, J, KB) load_lds16((const u16*)(pA + aofs[J] + (KB)), \
                                  lds + (NB) + tid * 8 + (J) * 4096)
#define STB(NB, J, KB) load_lds16((const u16*)(pB + bofs[J] + (KB)), \
                                  lds + (NB) + OB + tid * 8 + (J) * 4096)
#define RD_BB(CB) do {                                                        \
        _Pragma("unroll")                                                     \
        for (int j = 0; j < 4; ++j) {                                         \
            bb[j][0] = *(const f16x8*)(lds + (CB) + offB[j][0]);              \
            bb[j][1] = *(const f16x8*)(lds + (CB) + offB[j][1]);              \
        }                                                                     \
    } while (0)
#define PHASE(CB, I0, FIRST, STAGES, WAITST) do {                             \
        if (FIRST) RD_BB(CB);                                                 \
        f16x8 a00 = *(const f16x8*)(lds + (CB) + offA[(I0)][0]);              \
        f16x8 a01 = *(const f16x8*)(lds + (CB) + offA[(I0)][1]);              \
        f16x8 a10 = *(const f16x8*)(lds + (CB) + offA[(I0) + 1][0]);          \
        f16x8 a11 = *(const f16x8*)(lds + (CB) + offA[(I0) + 1][1]);          \
        STAGES;                                                               \
        if (FIRST) LGKM8();                                                   \
        SBAR();                                                               \
        LGKM0(); SCHB();                                                      \
        __builtin_amdgcn_s_setprio(1);                                        \
        _Pragma("unroll")                                                     \
        for (int j = 0; j < 4; ++j) {                                         \
            acc[(I0)][j]     = MFMA_F16(a00, bb[j][0], acc[(I0)][j]);         \
            acc[(I0)][j]     = MFMA_F16(a01, bb[j][1], acc[(I0)][j]);         \
            acc[(I0) + 1][j] = MFMA_F16(a10, bb[j][0], acc[(I0) + 1][j]);     \
            acc[(I0) + 1][j] = MFMA_F16(a11, bb[j][1], acc[(I0) + 1][j]);     \
        }                                                                     \
        __builtin_amdgcn_s_setprio(0);                                        \
        WAITST;                                                               \
        SBAR();                                                               \
    } while (0)

    constexpr int NT2 = 8;

    STB(0, 0, 0); STB(0, 1, 0); STB(0, 2, 0); STB(0, 3, 0);
    STA(0, 0, 0); STA(0, 1, 0); STA(0, 2, 0); STA(0, 3, 0);
    STB(BUFSZ, 0, 128); STB(BUFSZ, 1, 128); STB(BUFSZ, 2, 128); STB(BUFSZ, 3, 128);
    VMW4();
    SBAR();

    for (int it = 0; it < NT2; ++it) {
        const long long kb1 = (long long)(2 * it + 1) * 128;
        const long long kb2 = (long long)(2 * it + 2) * 128;
        const long long kb3 = (long long)(2 * it + 3) * 128;
        const bool st2 = (it + 1) < NT2;

        PHASE(0, 0, true,  { STA(BUFSZ, 0, kb1); STA(BUFSZ, 1, kb1); }, );
        PHASE(0, 2, false, { STA(BUFSZ, 2, kb1); STA(BUFSZ, 3, kb1); }, );
        PHASE(0, 4, false, { if (st2) { STB(0, 0, kb2); STB(0, 1, kb2); } }, );
        PHASE(0, 6, false, { if (st2) { STB(0, 2, kb2); STB(0, 3, kb2); } },
              { if (st2) { VMW4(); } else { VMW0(); } });
        PHASE(BUFSZ, 0, true,  { if (st2) { STA(0, 0, kb2); STA(0, 1, kb2); } }, );
        PHASE(BUFSZ, 2, false, { if (st2) { STA(0, 2, kb2); STA(0, 3, kb2); } }, );
        PHASE(BUFSZ, 4, false, { if (st2) { STB(BUFSZ, 0, kb3); STB(BUFSZ, 1, kb3); } }, );
        PHASE(BUFSZ, 6, false, { if (st2) { STB(BUFSZ, 2, kb3); STB(BUFSZ, 3, kb3); } },
              { if (st2) VMW4(); });
    }
#undef STA
#undef STB
#undef RD_BB
#undef PHASE

    const long long Cbase = z * sC;
#pragma unroll
    for (int i = 0; i < 8; ++i) {
        const int row0 = bm + wr * 128 + i * 16 + ((lane >> 4) << 2);
#pragma unroll
        for (int j = 0; j < 4; ++j) {
            const int col = bn + wc * 64 + j * 16 + (lane & 15);
#pragma unroll
            for (int e = 0; e < 4; ++e) {
                const float v = acc[i][j][e];
                const long long idx = Cbase + (long long)(row0 + e) * N + col;
                if constexpr (EPI == 0) Cf[idx] = v;
                else                    Cf[idx] = fmaxf(v, 0.f);
            }
        }
    }
}

// fused p+q pre-pass (p, q same shape -> same addressing, one launch):
// p -> p16 (fp16); q -> q_hi, q_lo (straight) and qT (transposed).
__global__ void fuse_cvt_pq(const float* __restrict__ p, const float* __restrict__ q,
                            u16* __restrict__ p16, u16* __restrict__ hi,
                            u16* __restrict__ lo, u16* __restrict__ thi)
{
    __shared__ float t[32][33];
    const long long z = blockIdx.z;
    const long long base = z * 1048576;
    const int r0 = blockIdx.y * 32, c0 = blockIdx.x * 32;
    for (int j = threadIdx.y; j < 32; j += 8) {
        const long long o = base + (long long)(r0 + j) * 1024 + c0 + threadIdx.x;
        p16[o] = f2h(p[o]);
        const float v = q[o];
        t[j][threadIdx.x] = v;
        const u16 h = f2h(v);
        hi[o] = h;
        lo[o] = f2h(v - h2f(h));
    }
    __syncthreads();
    for (int j = threadIdx.y; j < 32; j += 8)
        thi[base + (long long)(c0 + j) * 1024 + r0 + threadIdx.x] = f2h(t[threadIdx.x][j]);
}

// Wt[c][r] = W[r][c], fp16 single
__global__ void transpose_cvt_w(const float* __restrict__ in, u16* __restrict__ hi)
{
    __shared__ float t[32][33];
    const int r0 = blockIdx.y * 32, c0 = blockIdx.x * 32;
    for (int j = threadIdx.y; j < 32; j += 8)
        t[j][threadIdx.x] = in[(long long)(r0 + j) * 1024 + c0 + threadIdx.x];
    __syncthreads();
    for (int j = threadIdx.y; j < 32; j += 8)
        hi[(long long)(c0 + j) * 1024 + r0 + threadIdx.x] = f2h(t[threadIdx.x][j]);
}

// wave-per-row softmax (fp32 in, fp16 out). R22 FIX: each lane handles
// FOUR float4s (16 elems) -> 64 lanes x 16 = 1024 = full row (R21 bug:
// one float4/lane covered only 256 elems). float4 index lane + 64*k per
// k-slice -> consecutive lanes contiguous, fully coalesced. Pure shfl_xor
// reduction, no LDS / block barriers. 4 rows per 256-thread block.
__global__ void softmax_wave(const float* __restrict__ S, u16* __restrict__ A)
{
    const int lane = threadIdx.x & 63;
    const long long row = (long long)blockIdx.x * 4 + (threadIdx.x >> 6);
    const float4* rp = (const float4*)(S + row * (long long)LQ_N);
    float4 v[4];
#pragma unroll
    for (int k = 0; k < 4; ++k)
        v[k] = rp[lane + 64 * k];

    float m = -1e30f;
#pragma unroll
    for (int k = 0; k < 4; ++k)
        m = fmaxf(m, fmaxf(fmaxf(v[k].x, v[k].y), fmaxf(v[k].z, v[k].w)));
#pragma unroll
    for (int off = 32; off > 0; off >>= 1)
        m = fmaxf(m, __shfl_xor(m, off));

    float s = 0.f;
#pragma unroll
    for (int k = 0; k < 4; ++k) {
        v[k].x = __expf(v[k].x - m); v[k].y = __expf(v[k].y - m);
        v[k].z = __expf(v[k].z - m); v[k].w = __expf(v[k].w - m);
        s += v[k].x + v[k].y + v[k].z + v[k].w;
    }
#pragma unroll
    for (int off = 32; off > 0; off >>= 1)
        s += __shfl_xor(s, off);

    const float inv = 1.0f / s;
    ushort4* op = (ushort4*)(A + row * (long long)LQ_N);
#pragma unroll
    for (int k = 0; k < 4; ++k) {
        ushort4 o;
        o.x = f2h(v[k].x * inv); o.y = f2h(v[k].y * inv);
        o.z = f2h(v[k].z * inv); o.w = f2h(v[k].w * inv);
        op[lane + 64 * k] = o;
    }
}

// ---------------------------------------------------------------------------
// Fallback fp32 path (round-1, verified; needs only 128 MB ws)
// ---------------------------------------------------------------------------
#define BM 128
#define BN 128
#define BK 8
#define TM 8
#define TN 8

template<bool TRANSB, bool BIAS, bool RELU>
__launch_bounds__(256)
__global__ void gemm_k(const float* __restrict__ A, const float* __restrict__ Bmat,
                       const float* __restrict__ bias, float* __restrict__ C,
                       int M, int N, int K,
                       long long sA, long long sB, long long sC)
{
    __shared__ float As[BK][BM];
    __shared__ float Bs[BK][BN];
    const int tid = threadIdx.x;
    const int tx = tid & 15;
    const int ty = tid >> 4;
    const int bn = blockIdx.x * BN;
    const int bm = blockIdx.y * BM;
    const long long z = blockIdx.z;
    A += z * sA; Bmat += z * sB; C += z * sC;
    float acc[TM][TN];
#pragma unroll
    for (int i = 0; i < TM; i++)
#pragma unroll
        for (int j = 0; j < TN; j++) acc[i][j] = 0.f;
    const int arow = tid >> 1;
    const int acol = (tid & 1) * 4;
    const int bk_n = tid >> 5;
    const int bn_n = (tid & 31) * 4;
    for (int k0 = 0; k0 < K; k0 += BK) {
        float4 a4 = *(const float4*)&A[(long long)(bm + arow) * K + k0 + acol];
        As[acol + 0][arow] = a4.x; As[acol + 1][arow] = a4.y;
        As[acol + 2][arow] = a4.z; As[acol + 3][arow] = a4.w;
        if (TRANSB) {
            float4 b4 = *(const float4*)&Bmat[(long long)(bn + arow) * K + k0 + acol];
            Bs[acol + 0][arow] = b4.x; Bs[acol + 1][arow] = b4.y;
            Bs[acol + 2][arow] = b4.z; Bs[acol + 3][arow] = b4.w;
        } else {
            float4 b4 = *(const float4*)&Bmat[(long long)(k0 + bk_n) * N + bn + bn_n];
            *(float4*)&Bs[bk_n][bn_n] = b4;
        }
        __syncthreads();
#pragma unroll
        for (int k = 0; k < BK; k++) {
            float a[TM], b[TN];
            *(float4*)&a[0] = *(const float4*)&As[k][ty * TM];
            *(float4*)&a[4] = *(const float4*)&As[k][ty * TM + 4];
            *(float4*)&b[0] = *(const float4*)&Bs[k][tx * TN];
            *(float4*)&b[4] = *(const float4*)&Bs[k][tx * TN + 4];
#pragma unroll
            for (int i = 0; i < TM; i++)
#pragma unroll
                for (int j = 0; j < TN; j++)
                    acc[i][j] = fmaf(a[i], b[j], acc[i][j]);
        }
        __syncthreads();
    }
#pragma unroll
    for (int i = 0; i < TM; i++) {
        const int row = bm + ty * TM + i;
#pragma unroll
        for (int j = 0; j < TN; j += 4) {
            const int col = bn + tx * TN + j;
            float4 v;
            v.x = acc[i][j + 0]; v.y = acc[i][j + 1];
            v.z = acc[i][j + 2]; v.w = acc[i][j + 3];
            if (BIAS) {
                v.x += bias[col + 0]; v.y += bias[col + 1];
                v.z += bias[col + 2]; v.w += bias[col + 3];
            }
            if (RELU) {
                v.x = fmaxf(v.x, 0.f); v.y = fmaxf(v.y, 0.f);
                v.z = fmaxf(v.z, 0.f); v.w = fmaxf(v.w, 0.f);
            }
            *(float4*)&C[(long long)row * N + col] = v;
        }
    }
}

__global__ void softmax_k(float* __restrict__ S)
{
    const long long row = blockIdx.x;
    float* r = S + row * (long long)LQ_N;
    const int t = threadIdx.x;
    float4 v = ((float4*)r)[t];
    float m = fmaxf(fmaxf(v.x, v.y), fmaxf(v.z, v.w));
#pragma unroll
    for (int off = 32; off > 0; off >>= 1)
        m = fmaxf(m, __shfl_xor(m, off));
    __shared__ float red[4];
    const int lane = t & 63, wid = t >> 6;
    if (lane == 0) red[wid] = m;
    __syncthreads();
    m = fmaxf(fmaxf(red[0], red[1]), fmaxf(red[2], red[3]));
    __syncthreads();
    v.x = __expf(v.x - m); v.y = __expf(v.y - m);
    v.z = __expf(v.z - m); v.w = __expf(v.w - m);
    float s = v.x + v.y + v.z + v.w;
#pragma unroll
    for (int off = 32; off > 0; off >>= 1)
        s += __shfl_xor(s, off);
    if (lane == 0) red[wid] = s;
    __syncthreads();
    s = red[0] + red[1] + red[2] + red[3];
    const float inv = 1.0f / s;
    v.x *= inv; v.y *= inv; v.z *= inv; v.w *= inv;
    ((float4*)r)[t] = v;
}

extern "C" void kernel_launch(void* const* d_in, const int* in_sizes, int n_in,
                              void* d_out, int out_size, void* d_ws, size_t ws_size,
                              hipStream_t stream)
{
    const float* p    = (const float*)d_in[0];
    const float* q    = (const float*)d_in[1];
    const float* W    = (const float*)d_in[2];
    const float* bias = (const float*)d_in[3];
    float* out = (float*)d_out;

    const size_t MB32 = 33554432ull;                 // 32 MB unit
    const size_t NEED = 5 * MB32 + 2097152ull;       // 162 MB

    if (ws_size >= NEED) {
        char* w = (char*)d_ws;
        u16* p16   = (u16*)(w + 0 * MB32);
        u16* q_hi  = (u16*)(w + 1 * MB32);
        u16* q_lo  = (u16*)(w + 2 * MB32);
        u16* keys  = (u16*)(w + 3 * MB32);
        u16* qT    = (u16*)(w + 4 * MB32);
        u16* Wt    = (u16*)(w + 5 * MB32);
        float* scores = (float*)(w + 1 * MB32);  // reuses q_hi/q_lo after GEMM1
        u16* attn     = (u16*)(w + 0 * MB32);    // reuses p16 after GEMM2

        fuse_cvt_pq<<<dim3(32, 32, B_N), dim3(32, 8), 0, stream>>>(
            p, q, p16, q_hi, q_lo, qT);
        transpose_cvt_w<<<dim3(32, 32, 1), dim3(32, 8), 0, stream>>>(W, Wt);

        // keys = (q_hi + q_lo) @ Wt + b : BK32 split 2-barrier (R19 config).
        gemm2t<true, 1><<<256, 512, 0, stream>>>(
            q_hi, q_lo, Wt, bias, nullptr, keys,
            H_N, /*gn=*/4, /*gmn=*/256, 0, 0, 0);

        // scores[b] = p16[b] @ keys[b]^T : 8-phase dense (R19-verified).
        gemm_p8<0><<<256, 512, 0, stream>>>(
            p16, keys, scores,
            LQ_N, /*gn=*/4, /*gmn=*/16,
            (long long)LP_N * H_N, (long long)LQ_N * H_N, (long long)LP_N * LQ_N);

        softmax_wave<<<(B_N * LP_N) / 4, 256, 0, stream>>>(scores, attn);

        // out[b] = relu(attn[b] @ q[b]) : 8-phase dense (R19-verified).
        gemm_p8<2><<<256, 512, 0, stream>>>(
            attn, qT, out,
            H_N, /*gn=*/4, /*gmn=*/16,
            (long long)LP_N * LQ_N, (long long)H_N * LQ_N, (long long)LP_N * H_N);
    } else {
        float* keys   = (float*)d_ws;
        float* scores = keys + (long long)B_N * LQ_N * H_N;

        gemm_k<false, true, false><<<dim3(H_N / BN, (B_N * LQ_N) / BM, 1), 256, 0, stream>>>(
            q, W, bias, keys, B_N * LQ_N, H_N, H_N, 0, 0, 0);
        gemm_k<true, false, false><<<dim3(LQ_N / BN, LP_N / BM, B_N), 256, 0, stream>>>(
            p, keys, nullptr, scores, LP_N, LQ_N, H_N,
            (long long)LP_N * H_N, (long long)LQ_N * H_N, (long long)LP_N * LQ_N);
        softmax_k<<<B_N * LP_N, 256, 0, stream>>>(scores);
        gemm_k<false, false, true><<<dim3(H_N / BN, LP_N / BM, B_N), 256, 0, stream>>>(
            scores, q, nullptr, out, LP_N, H_N, LQ_N,
            (long long)LP_N * LQ_N, (long long)LQ_N * H_N, (long long)LP_N * H_N);
    }
}

// Round 23
// 206.476 us; speedup vs baseline: 1.0768x; 1.0532x over previous
//
#include <hip/hip_runtime.h>
#include <hip/hip_bf16.h>

#define B_N 16
#define LP_N 1024
#define LQ_N 1024
#define H_N 1024

typedef unsigned short u16;
typedef __attribute__((ext_vector_type(8))) _Float16 f16x8;
typedef __attribute__((ext_vector_type(4))) float f32x4;

__device__ __forceinline__ u16 f2h(float x) {
    _Float16 h = (_Float16)x;
    return *(u16*)&h;
}
__device__ __forceinline__ float h2f(u16 u) {
    _Float16 h;
    *(u16*)&h = u;
    return (float)h;
}

__device__ __forceinline__ void load_lds16(const u16* g, u16* l) {
    __builtin_amdgcn_global_load_lds(
        (const __attribute__((address_space(1))) void*)g,
        (__attribute__((address_space(3))) void*)l, 16, 0, 0);
}

#define MFMA_F16(a, b, c) __builtin_amdgcn_mfma_f32_16x16x32_f16(a, b, c, 0, 0, 0)
#define VMW0()  asm volatile("s_waitcnt vmcnt(0)" ::: "memory")
#define VMW4()  asm volatile("s_waitcnt vmcnt(4)" ::: "memory")
#define LGKM8() asm volatile("s_waitcnt lgkmcnt(8)" ::: "memory")
#define LGKM0() asm volatile("s_waitcnt lgkmcnt(0)" ::: "memory")
#define SCHB()  __builtin_amdgcn_sched_barrier(0)
#define SBAR()  __builtin_amdgcn_s_barrier()

// ---------------------------------------------------------------------------
// GEMM1 (R15/R19-verified config): 256x256 fp16 split, BK=32, dbuf, per-tile
// vmcnt(0)+s_barrier gate.
// ---------------------------------------------------------------------------
template<bool SPLIT, int EPI>
__launch_bounds__(512, 2)
__global__ void gemm2t(const u16* __restrict__ Ahi, const u16* __restrict__ Alo,
                       const u16* __restrict__ Bm,
                       const float* __restrict__ bias,
                       float* __restrict__ Cf, u16* __restrict__ Ch,
                       int N, int gn, int gmn,
                       long long sA, long long sB, long long sC)
{
    constexpr int REG  = 8192;
    constexpr int O_AL = REG;
    constexpr int O_B  = SPLIT ? 2 * REG : REG;
    constexpr int BUF  = SPLIT ? 3 * REG : 2 * REG;
    __shared__ __align__(16) u16 lds[2 * BUF];

    const int tid  = threadIdx.x;
    const int lane = tid & 63;
    const int wv   = tid >> 6;
    const int wr   = wv >> 2, wc = wv & 3;

    const int d   = blockIdx.x;
    const int cpx = gridDim.x >> 3;
    const int swz = (d & 7) * cpx + (d >> 3);
    const long long z = swz / gmn;
    const int r_  = swz % gmn;
    const int bm  = (r_ / gn) * 256;
    const int bn  = (r_ % gn) * 256;

    const char* pAh = (const char*)(Ahi + z * sA);
    const char* pAl = (const char*)(Alo + z * sA);
    const char* pB  = (const char*)(Bm + z * sB);

    const int r0 = tid >> 2;
    const int xc = (tid & 3) ^ ((r0 >> 1) & 3);
    const long long aof = (long long)(bm + r0) * 2048 + xc * 16;
    const long long bof = (long long)(bn + r0) * 2048 + xc * 16;
    const long long ao2 = aof + 128 * 2048;
    const long long bo2 = bof + 128 * 2048;
    const int d0 = tid * 8;
    const int d1 = d0 + 4096;

    int offA[8], offB[4];
#pragma unroll
    for (int i = 0; i < 8; ++i) {
        const int r = wr * 128 + i * 16 + (lane & 15);
        offA[i] = r * 32 + ((((lane >> 4) ^ (r >> 1)) & 3) << 3);
    }
#pragma unroll
    for (int j = 0; j < 4; ++j) {
        const int r = wc * 64 + j * 16 + (lane & 15);
        offB[j] = r * 32 + ((((lane >> 4) ^ (r >> 1)) & 3) << 3);
    }

    f32x4 acc[8][4];
#pragma unroll
    for (int i = 0; i < 8; ++i)
#pragma unroll
        for (int j = 0; j < 4; ++j)
            acc[i][j] = (f32x4){0.f, 0.f, 0.f, 0.f};

#define STG(NB, KB) do {                                                      \
        load_lds16((const u16*)(pAh + aof + (KB)), lds + (NB) + d0);          \
        load_lds16((const u16*)(pAh + ao2 + (KB)), lds + (NB) + d1);          \
        load_lds16((const u16*)(pB + bof + (KB)), lds + (NB) + O_B + d0);     \
        load_lds16((const u16*)(pB + bo2 + (KB)), lds + (NB) + O_B + d1);     \
        if constexpr (SPLIT) {                                                \
            load_lds16((const u16*)(pAl + aof + (KB)), lds + (NB) + O_AL + d0); \
            load_lds16((const u16*)(pAl + ao2 + (KB)), lds + (NB) + O_AL + d1); \
        }                                                                     \
    } while (0)

#define TERM(AF, BF) do {                                                     \
        __builtin_amdgcn_s_setprio(1);                                        \
        _Pragma("unroll")                                                     \
        for (int i = 0; i < 8; ++i)                                           \
            _Pragma("unroll")                                                 \
            for (int j = 0; j < 4; ++j)                                       \
                acc[i][j] = MFMA_F16(AF[i], BF[j], acc[i][j]);                \
        __builtin_amdgcn_s_setprio(0);                                        \
    } while (0)

    constexpr int NT = 32;

    STG(0, 0);

    for (int t = 0; t < NT; ++t) {
        const int cb = (t & 1) ? BUF : 0;
        const int nb = (t & 1) ? 0 : BUF;
        const long long kb = (long long)(t + 1) * 64;

        VMW0();
        SBAR();
        f16x8 b[4], ah[8], al[8];
#pragma unroll
        for (int j = 0; j < 4; ++j)
            b[j] = *(const f16x8*)(lds + cb + O_B + offB[j]);
#pragma unroll
        for (int i = 0; i < 8; ++i)
            ah[i] = *(const f16x8*)(lds + cb + offA[i]);
        if constexpr (SPLIT) {
#pragma unroll
            for (int i = 0; i < 8; ++i)
                al[i] = *(const f16x8*)(lds + cb + O_AL + offA[i]);
        }
        if (t + 1 < NT) STG(nb, kb);
        if constexpr (SPLIT) { LGKM8(); } else { LGKM0(); }
        SCHB();
        TERM(ah, b);
        if constexpr (SPLIT) {
            LGKM0(); SCHB();
            TERM(al, b);
        }
    }
#undef STG
#undef TERM

    const long long Cbase = z * sC;
#pragma unroll
    for (int i = 0; i < 8; ++i) {
        const int row0 = bm + wr * 128 + i * 16 + ((lane >> 4) << 2);
#pragma unroll
        for (int j = 0; j < 4; ++j) {
            const int col = bn + wc * 64 + j * 16 + (lane & 15);
#pragma unroll
            for (int e = 0; e < 4; ++e) {
                const float v = acc[i][j][e];
                const long long idx = Cbase + (long long)(row0 + e) * N + col;
                if constexpr (EPI == 0) {
                    Cf[idx] = v;
                } else if constexpr (EPI == 1) {
                    Ch[idx] = f2h(v + bias[col]);
                } else {
                    Cf[idx] = fmaxf(v, 0.f);
                }
            }
        }
    }
}

// ---------------------------------------------------------------------------
// R19 dense GEMM (verified): faithful m201 8-phase, 256x256, BK=64, dbuf
// 128KB, 2 K-tiles/iteration, counted vmcnt(4) at ph3/ph7.
// ---------------------------------------------------------------------------
template<int EPI>
__launch_bounds__(512, 2)
__global__ void gemm_p8(const u16* __restrict__ Am, const u16* __restrict__ Bm,
                        float* __restrict__ Cf,
                        int N, int gn, int gmn,
                        long long sA, long long sB, long long sC)
{
    constexpr int OB    = 16384;
    constexpr int BUFSZ = 32768;
    __shared__ __align__(16) u16 lds[2 * BUFSZ];

    const int tid  = threadIdx.x;
    const int lane = tid & 63;
    const int wv   = tid >> 6;
    const int wr   = wv >> 2, wc = wv & 3;

    const int d   = blockIdx.x;
    const int cpx = gridDim.x >> 3;
    const int swz = (d & 7) * cpx + (d >> 3);
    const long long z = swz / gmn;
    const int r_  = swz % gmn;
    const int bm  = (r_ / gn) * 256;
    const int bn  = (r_ % gn) * 256;

    const char* pA = (const char*)(Am + z * sA);
    const char* pB = (const char*)(Bm + z * sB);

    const int rr  = tid >> 3;
    const int xcv = (tid & 7) ^ (rr & 7);
    long long aofs[4], bofs[4];
#pragma unroll
    for (int j = 0; j < 4; ++j) {
        aofs[j] = (long long)(bm + rr + j * 64) * 2048 + xcv * 16;
        bofs[j] = (long long)(bn + rr + j * 64) * 2048 + xcv * 16;
    }

    int offA[8][2], offB[4][2];
#pragma unroll
    for (int i = 0; i < 8; ++i) {
        const int r = wr * 128 + i * 16 + (lane & 15);
#pragma unroll
        for (int s = 0; s < 2; ++s)
            offA[i][s] = r * 64 + ((((s * 4 + (lane >> 4)) ^ r) & 7) << 3);
    }
#pragma unroll
    for (int j = 0; j < 4; ++j) {
        const int r = wc * 64 + j * 16 + (lane & 15);
#pragma unroll
        for (int s = 0; s < 2; ++s)
            offB[j][s] = OB + r * 64 + ((((s * 4 + (lane >> 4)) ^ r) & 7) << 3);
    }

    f32x4 acc[8][4];
#pragma unroll
    for (int i = 0; i < 8; ++i)
#pragma unroll
        for (int j = 0; j < 4; ++j)
            acc[i][j] = (f32x4){0.f, 0.f, 0.f, 0.f};

    f16x8 bb[4][2];

#define STA(NB, J, KB) load_lds16((const u16*)(pA + aofs[J] + (KB)), \
                                  lds + (NB) + tid * 8 + (J) * 4096)
#define STB(NB, J, KB) load_lds16((const u16*)(pB + bofs[J] + (KB)), \
                                  lds + (NB) + OB + tid * 8 + (J) * 4096)
#define RD_BB(CB) do {                                                        \
        _Pragma("unroll")                                                     \
        for (int j = 0; j < 4; ++j) {                                         \
            bb[j][0] = *(const f16x8*)(lds + (CB) + offB[j][0]);              \
            bb[j][1] = *(const f16x8*)(lds + (CB) + offB[j][1]);              \
        }                                                                     \
    } while (0)
#define PHASE(CB, I0, FIRST, STAGES, WAITST) do {                             \
        if (FIRST) RD_BB(CB);                                                 \
        f16x8 a00 = *(const f16x8*)(lds + (CB) + offA[(I0)][0]);              \
        f16x8 a01 = *(const f16x8*)(lds + (CB) + offA[(I0)][1]);              \
        f16x8 a10 = *(const f16x8*)(lds + (CB) + offA[(I0) + 1][0]);          \
        f16x8 a11 = *(const f16x8*)(lds + (CB) + offA[(I0) + 1][1]);          \
        STAGES;                                                               \
        if (FIRST) LGKM8();                                                   \
        SBAR();                                                               \
        LGKM0(); SCHB();                                                      \
        __builtin_amdgcn_s_setprio(1);                                        \
        _Pragma("unroll")                                                     \
        for (int j = 0; j < 4; ++j) {                                         \
            acc[(I0)][j]     = MFMA_F16(a00, bb[j][0], acc[(I0)][j]);         \
            acc[(I0)][j]     = MFMA_F16(a01, bb[j][1], acc[(I0)][j]);         \
            acc[(I0) + 1][j] = MFMA_F16(a10, bb[j][0], acc[(I0) + 1][j]);     \
            acc[(I0) + 1][j] = MFMA_F16(a11, bb[j][1], acc[(I0) + 1][j]);     \
        }                                                                     \
        __builtin_amdgcn_s_setprio(0);                                        \
        WAITST;                                                               \
        SBAR();                                                               \
    } while (0)

    constexpr int NT2 = 8;

    STB(0, 0, 0); STB(0, 1, 0); STB(0, 2, 0); STB(0, 3, 0);
    STA(0, 0, 0); STA(0, 1, 0); STA(0, 2, 0); STA(0, 3, 0);
    STB(BUFSZ, 0, 128); STB(BUFSZ, 1, 128); STB(BUFSZ, 2, 128); STB(BUFSZ, 3, 128);
    VMW4();
    SBAR();

    for (int it = 0; it < NT2; ++it) {
        const long long kb1 = (long long)(2 * it + 1) * 128;
        const long long kb2 = (long long)(2 * it + 2) * 128;
        const long long kb3 = (long long)(2 * it + 3) * 128;
        const bool st2 = (it + 1) < NT2;

        PHASE(0, 0, true,  { STA(BUFSZ, 0, kb1); STA(BUFSZ, 1, kb1); }, );
        PHASE(0, 2, false, { STA(BUFSZ, 2, kb1); STA(BUFSZ, 3, kb1); }, );
        PHASE(0, 4, false, { if (st2) { STB(0, 0, kb2); STB(0, 1, kb2); } }, );
        PHASE(0, 6, false, { if (st2) { STB(0, 2, kb2); STB(0, 3, kb2); } },
              { if (st2) { VMW4(); } else { VMW0(); } });
        PHASE(BUFSZ, 0, true,  { if (st2) { STA(0, 0, kb2); STA(0, 1, kb2); } }, );
        PHASE(BUFSZ, 2, false, { if (st2) { STA(0, 2, kb2); STA(0, 3, kb2); } }, );
        PHASE(BUFSZ, 4, false, { if (st2) { STB(BUFSZ, 0, kb3); STB(BUFSZ, 1, kb3); } }, );
        PHASE(BUFSZ, 6, false, { if (st2) { STB(BUFSZ, 2, kb3); STB(BUFSZ, 3, kb3); } },
              { if (st2) VMW4(); });
    }
#undef STA
#undef STB
#undef RD_BB
#undef PHASE

    const long long Cbase = z * sC;
#pragma unroll
    for (int i = 0; i < 8; ++i) {
        const int row0 = bm + wr * 128 + i * 16 + ((lane >> 4) << 2);
#pragma unroll
        for (int j = 0; j < 4; ++j) {
            const int col = bn + wc * 64 + j * 16 + (lane & 15);
#pragma unroll
            for (int e = 0; e < 4; ++e) {
                const float v = acc[i][j][e];
                const long long idx = Cbase + (long long)(row0 + e) * N + col;
                if constexpr (EPI == 0) Cf[idx] = v;
                else                    Cf[idx] = fmaxf(v, 0.f);
            }
        }
    }
}

// R23: fully-vectorized streaming pre-pass (float4 in, ushort4 out):
// p -> p16; q -> q_hi, q_lo. 224MB total @ streaming BW.
__global__ void cvt_pq_vec(const float4* __restrict__ p, const float4* __restrict__ q,
                           ushort4* __restrict__ p16, ushort4* __restrict__ hi,
                           ushort4* __restrict__ lo, long long n4)
{
    const long long i = (long long)blockIdx.x * 256 + threadIdx.x;
    if (i >= n4) return;
    const float4 a = p[i];
    ushort4 hp;
    hp.x = f2h(a.x); hp.y = f2h(a.y); hp.z = f2h(a.z); hp.w = f2h(a.w);
    p16[i] = hp;
    const float4 b = q[i];
    ushort4 hq, lq;
    hq.x = f2h(b.x); lq.x = f2h(b.x - h2f(hq.x));
    hq.y = f2h(b.y); lq.y = f2h(b.y - h2f(hq.y));
    hq.z = f2h(b.z); lq.z = f2h(b.z - h2f(hq.z));
    hq.w = f2h(b.w); lq.w = f2h(b.w - h2f(hq.w));
    hi[i] = hq;
    lo[i] = lq;
}

// R23: fp16 transpose qT[c][r] = q_hi[r][c], per batch z. 64x64 u16 tiles,
// ushort4 global loads/stores (coalesced 128B runs), scalar LDS (pad 68).
__global__ void transpose_h(const u16* __restrict__ in, u16* __restrict__ out)
{
    __shared__ u16 t[64][68];
    const long long base = (long long)blockIdx.z * 1048576;
    const int r0 = blockIdx.y * 64, c0 = blockIdx.x * 64;
    const int tid = threadIdx.x;
    const int rl = tid >> 4;            // 0..15
    const int cl = (tid & 15) * 4;      // 0..60
#pragma unroll
    for (int pp = 0; pp < 4; ++pp) {
        const int r = pp * 16 + rl;
        const ushort4 v = *(const ushort4*)&in[base + (long long)(r0 + r) * 1024 + c0 + cl];
        t[r][cl + 0] = v.x; t[r][cl + 1] = v.y;
        t[r][cl + 2] = v.z; t[r][cl + 3] = v.w;
    }
    __syncthreads();
#pragma unroll
    for (int pp = 0; pp < 4; ++pp) {
        const int c = pp * 16 + rl;     // output row = original col
        const int r = cl;               // output col group = original rows
        ushort4 o;
        o.x = t[r + 0][c]; o.y = t[r + 1][c];
        o.z = t[r + 2][c]; o.w = t[r + 3][c];
        *(ushort4*)&out[base + (long long)(c0 + c) * 1024 + r0 + r] = o;
    }
}

// Wt[c][r] = W[r][c], fp16 single (1024x1024, one batch)
__global__ void transpose_cvt_w(const float* __restrict__ in, u16* __restrict__ hi)
{
    __shared__ float t[32][33];
    const int r0 = blockIdx.y * 32, c0 = blockIdx.x * 32;
    for (int j = threadIdx.y; j < 32; j += 8)
        t[j][threadIdx.x] = in[(long long)(r0 + j) * 1024 + c0 + threadIdx.x];
    __syncthreads();
    for (int j = threadIdx.y; j < 32; j += 8)
        hi[(long long)(c0 + j) * 1024 + r0 + threadIdx.x] = f2h(t[threadIdx.x][j]);
}

// wave-per-row softmax (R22-verified): 64 lanes x 4 float4 = 1024 elems.
__global__ void softmax_wave(const float* __restrict__ S, u16* __restrict__ A)
{
    const int lane = threadIdx.x & 63;
    const long long row = (long long)blockIdx.x * 4 + (threadIdx.x >> 6);
    const float4* rp = (const float4*)(S + row * (long long)LQ_N);
    float4 v[4];
#pragma unroll
    for (int k = 0; k < 4; ++k)
        v[k] = rp[lane + 64 * k];

    float m = -1e30f;
#pragma unroll
    for (int k = 0; k < 4; ++k)
        m = fmaxf(m, fmaxf(fmaxf(v[k].x, v[k].y), fmaxf(v[k].z, v[k].w)));
#pragma unroll
    for (int off = 32; off > 0; off >>= 1)
        m = fmaxf(m, __shfl_xor(m, off));

    float s = 0.f;
#pragma unroll
    for (int k = 0; k < 4; ++k) {
        v[k].x = __expf(v[k].x - m); v[k].y = __expf(v[k].y - m);
        v[k].z = __expf(v[k].z - m); v[k].w = __expf(v[k].w - m);
        s += v[k].x + v[k].y + v[k].z + v[k].w;
    }
#pragma unroll
    for (int off = 32; off > 0; off >>= 1)
        s += __shfl_xor(s, off);

    const float inv = 1.0f / s;
    ushort4* op = (ushort4*)(A + row * (long long)LQ_N);
#pragma unroll
    for (int k = 0; k < 4; ++k) {
        ushort4 o;
        o.x = f2h(v[k].x * inv); o.y = f2h(v[k].y * inv);
        o.z = f2h(v[k].z * inv); o.w = f2h(v[k].w * inv);
        op[lane + 64 * k] = o;
    }
}

// ---------------------------------------------------------------------------
// Fallback fp32 path (round-1, verified; needs only 128 MB ws)
// ---------------------------------------------------------------------------
#define BM 128
#define BN 128
#define BK 8
#define TM 8
#define TN 8

template<bool TRANSB, bool BIAS, bool RELU>
__launch_bounds__(256)
__global__ void gemm_k(const float* __restrict__ A, const float* __restrict__ Bmat,
                       const float* __restrict__ bias, float* __restrict__ C,
                       int M, int N, int K,
                       long long sA, long long sB, long long sC)
{
    __shared__ float As[BK][BM];
    __shared__ float Bs[BK][BN];
    const int tid = threadIdx.x;
    const int tx = tid & 15;
    const int ty = tid >> 4;
    const int bn = blockIdx.x * BN;
    const int bm = blockIdx.y * BM;
    const long long z = blockIdx.z;
    A += z * sA; Bmat += z * sB; C += z * sC;
    float acc[TM][TN];
#pragma unroll
    for (int i = 0; i < TM; i++)
#pragma unroll
        for (int j = 0; j < TN; j++) acc[i][j] = 0.f;
    const int arow = tid >> 1;
    const int acol = (tid & 1) * 4;
    const int bk_n = tid >> 5;
    const int bn_n = (tid & 31) * 4;
    for (int k0 = 0; k0 < K; k0 += BK) {
        float4 a4 = *(const float4*)&A[(long long)(bm + arow) * K + k0 + acol];
        As[acol + 0][arow] = a4.x; As[acol + 1][arow] = a4.y;
        As[acol + 2][arow] = a4.z; As[acol + 3][arow] = a4.w;
        if (TRANSB) {
            float4 b4 = *(const float4*)&Bmat[(long long)(bn + arow) * K + k0 + acol];
            Bs[acol + 0][arow] = b4.x; Bs[acol + 1][arow] = b4.y;
            Bs[acol + 2][arow] = b4.z; Bs[acol + 3][arow] = b4.w;
        } else {
            float4 b4 = *(const float4*)&Bmat[(long long)(k0 + bk_n) * N + bn + bn_n];
            *(float4*)&Bs[bk_n][bn_n] = b4;
        }
        __syncthreads();
#pragma unroll
        for (int k = 0; k < BK; k++) {
            float a[TM], b[TN];
            *(float4*)&a[0] = *(const float4*)&As[k][ty * TM];
            *(float4*)&a[4] = *(const float4*)&As[k][ty * TM + 4];
            *(float4*)&b[0] = *(const float4*)&Bs[k][tx * TN];
            *(float4*)&b[4] = *(const float4*)&Bs[k][tx * TN + 4];
#pragma unroll
            for (int i = 0; i < TM; i++)
#pragma unroll
                for (int j = 0; j < TN; j++)
                    acc[i][j] = fmaf(a[i], b[j], acc[i][j]);
        }
        __syncthreads();
    }
#pragma unroll
    for (int i = 0; i < TM; i++) {
        const int row = bm + ty * TM + i;
#pragma unroll
        for (int j = 0; j < TN; j += 4) {
            const int col = bn + tx * TN + j;
            float4 v;
            v.x = acc[i][j + 0]; v.y = acc[i][j + 1];
            v.z = acc[i][j + 2]; v.w = acc[i][j + 3];
            if (BIAS) {
                v.x += bias[col + 0]; v.y += bias[col + 1];
                v.z += bias[col + 2]; v.w += bias[col + 3];
            }
            if (RELU) {
                v.x = fmaxf(v.x, 0.f); v.y = fmaxf(v.y, 0.f);
                v.z = fmaxf(v.z, 0.f); v.w = fmaxf(v.w, 0.f);
            }
            *(float4*)&C[(long long)row * N + col] = v;
        }
    }
}

__global__ void softmax_k(float* __restrict__ S)
{
    const long long row = blockIdx.x;
    float* r = S + row * (long long)LQ_N;
    const int t = threadIdx.x;
    float4 v = ((float4*)r)[t];
    float m = fmaxf(fmaxf(v.x, v.y), fmaxf(v.z, v.w));
#pragma unroll
    for (int off = 32; off > 0; off >>= 1)
        m = fmaxf(m, __shfl_xor(m, off));
    __shared__ float red[4];
    const int lane = t & 63, wid = t >> 6;
    if (lane == 0) red[wid] = m;
    __syncthreads();
    m = fmaxf(fmaxf(red[0], red[1]), fmaxf(red[2], red[3]));
    __syncthreads();
    v.x = __expf(v.x - m); v.y = __expf(v.y - m);
    v.z = __expf(v.z - m); v.w = __expf(v.w - m);
    float s = v.x + v.y + v.z + v.w;
#pragma unroll
    for (int off = 32; off > 0; off >>= 1)
        s += __shfl_xor(s, off);
    if (lane == 0) red[wid] = s;
    __syncthreads();
    s = red[0] + red[1] + red[2] + red[3];
    const float inv = 1.0f / s;
    v.x *= inv; v.y *= inv; v.z *= inv; v.w *= inv;
    ((float4*)r)[t] = v;
}

extern "C" void kernel_launch(void* const* d_in, const int* in_sizes, int n_in,
                              void* d_out, int out_size, void* d_ws, size_t ws_size,
                              hipStream_t stream)
{
    const float* p    = (const float*)d_in[0];
    const float* q    = (const float*)d_in[1];
    const float* W    = (const float*)d_in[2];
    const float* bias = (const float*)d_in[3];
    float* out = (float*)d_out;

    const size_t MB32 = 33554432ull;                 // 32 MB unit
    const size_t NEED = 5 * MB32 + 2097152ull;       // 162 MB

    if (ws_size >= NEED) {
        char* w = (char*)d_ws;
        u16* p16   = (u16*)(w + 0 * MB32);
        u16* q_hi  = (u16*)(w + 1 * MB32);
        u16* q_lo  = (u16*)(w + 2 * MB32);
        u16* keys  = (u16*)(w + 3 * MB32);
        u16* qT    = (u16*)(w + 4 * MB32);
        u16* Wt    = (u16*)(w + 5 * MB32);
        float* scores = (float*)(w + 1 * MB32);  // reuses q_hi/q_lo after GEMM1
        u16* attn     = (u16*)(w + 0 * MB32);    // reuses p16 after GEMM2

        const long long n4 = (long long)B_N * LQ_N * H_N / 4;
        cvt_pq_vec<<<(unsigned)(n4 / 256), 256, 0, stream>>>(
            (const float4*)p, (const float4*)q,
            (ushort4*)p16, (ushort4*)q_hi, (ushort4*)q_lo, n4);
        transpose_h<<<dim3(16, 16, B_N), 256, 0, stream>>>(q_hi, qT);
        transpose_cvt_w<<<dim3(32, 32, 1), dim3(32, 8), 0, stream>>>(W, Wt);

        // keys = (q_hi + q_lo) @ Wt + b : BK32 split 2-barrier (verified).
        gemm2t<true, 1><<<256, 512, 0, stream>>>(
            q_hi, q_lo, Wt, bias, nullptr, keys,
            H_N, /*gn=*/4, /*gmn=*/256, 0, 0, 0);

        // scores[b] = p16[b] @ keys[b]^T : 8-phase dense (verified).
        gemm_p8<0><<<256, 512, 0, stream>>>(
            p16, keys, scores,
            LQ_N, /*gn=*/4, /*gmn=*/16,
            (long long)LP_N * H_N, (long long)LQ_N * H_N, (long long)LP_N * LQ_N);

        softmax_wave<<<(B_N * LP_N) / 4, 256, 0, stream>>>(scores, attn);

        // out[b] = relu(attn[b] @ q[b]) : 8-phase dense (verified).
        gemm_p8<2><<<256, 512, 0, stream>>>(
            attn, qT, out,
            H_N, /*gn=*/4, /*gmn=*/16,
            (long long)LP_N * LQ_N, (long long)H_N * LQ_N, (long long)LP_N * H_N);
    } else {
        float* keys   = (float*)d_ws;
        float* scores = keys + (long long)B_N * LQ_N * H_N;

        gemm_k<false, true, false><<<dim3(H_N / BN, (B_N * LQ_N) / BM, 1), 256, 0, stream>>>(
            q, W, bias, keys, B_N * LQ_N, H_N, H_N, 0, 0, 0);
        gemm_k<true, false, false><<<dim3(LQ_N / BN, LP_N / BM, B_N), 256, 0, stream>>>(
            p, keys, nullptr, scores, LP_N, LQ_N, H_N,
            (long long)LP_N * H_N, (long long)LQ_N * H_N, (long long)LP_N * LQ_N);
        softmax_k<<<B_N * LP_N, 256, 0, stream>>>(scores);
        gemm_k<false, false, true><<<dim3(H_N / BN, LP_N / BM, B_N), 256, 0, stream>>>(
            scores, q, nullptr, out, LP_N, H_N, LQ_N,
            (long long)LP_N * LQ_N, (long long)LQ_N * H_N, (long long)LP_N * H_N);
    }
}

// Round 24
// 204.695 us; speedup vs baseline: 1.0862x; 1.0087x over previous
//
#include <hip/hip_runtime.h>
#include <hip/hip_bf16.h>

#define B_N 16
#define LP_N 1024
#define LQ_N 1024
#define H_N 1024

typedef unsigned short u16;
typedef __attribute__((ext_vector_type(8))) _Float16 f16x8;
typedef __attribute__((ext_vector_type(4))) float f32x4;

__device__ __forceinline__ u16 f2h(float x) {
    _Float16 h = (_Float16)x;
    return *(u16*)&h;
}
__device__ __forceinline__ float h2f(u16 u) {
    _Float16 h;
    *(u16*)&h = u;
    return (float)h;
}

__device__ __forceinline__ void load_lds16(const u16* g, u16* l) {
    __builtin_amdgcn_global_load_lds(
        (const __attribute__((address_space(1))) void*)g,
        (__attribute__((address_space(3))) void*)l, 16, 0, 0);
}

#define MFMA_F16(a, b, c) __builtin_amdgcn_mfma_f32_16x16x32_f16(a, b, c, 0, 0, 0)
#define VMW0()  asm volatile("s_waitcnt vmcnt(0)" ::: "memory")
#define VMW4()  asm volatile("s_waitcnt vmcnt(4)" ::: "memory")
#define LGKM8() asm volatile("s_waitcnt lgkmcnt(8)" ::: "memory")
#define LGKM0() asm volatile("s_waitcnt lgkmcnt(0)" ::: "memory")
#define SCHB()  __builtin_amdgcn_sched_barrier(0)
#define SBAR()  __builtin_amdgcn_s_barrier()

// ---------------------------------------------------------------------------
// GEMM1 (R15/R19-verified config): 256x256 fp16 split, BK=32, dbuf, per-tile
// vmcnt(0)+s_barrier gate.
// ---------------------------------------------------------------------------
template<bool SPLIT, int EPI>
__launch_bounds__(512, 2)
__global__ void gemm2t(const u16* __restrict__ Ahi, const u16* __restrict__ Alo,
                       const u16* __restrict__ Bm,
                       const float* __restrict__ bias,
                       float* __restrict__ Cf, u16* __restrict__ Ch,
                       int N, int gn, int gmn,
                       long long sA, long long sB, long long sC)
{
    constexpr int REG  = 8192;
    constexpr int O_AL = REG;
    constexpr int O_B  = SPLIT ? 2 * REG : REG;
    constexpr int BUF  = SPLIT ? 3 * REG : 2 * REG;
    __shared__ __align__(16) u16 lds[2 * BUF];

    const int tid  = threadIdx.x;
    const int lane = tid & 63;
    const int wv   = tid >> 6;
    const int wr   = wv >> 2, wc = wv & 3;

    const int d   = blockIdx.x;
    const int cpx = gridDim.x >> 3;
    const int swz = (d & 7) * cpx + (d >> 3);
    const long long z = swz / gmn;
    const int r_  = swz % gmn;
    const int bm  = (r_ / gn) * 256;
    const int bn  = (r_ % gn) * 256;

    const char* pAh = (const char*)(Ahi + z * sA);
    const char* pAl = (const char*)(Alo + z * sA);
    const char* pB  = (const char*)(Bm + z * sB);

    const int r0 = tid >> 2;
    const int xc = (tid & 3) ^ ((r0 >> 1) & 3);
    const long long aof = (long long)(bm + r0) * 2048 + xc * 16;
    const long long bof = (long long)(bn + r0) * 2048 + xc * 16;
    const long long ao2 = aof + 128 * 2048;
    const long long bo2 = bof + 128 * 2048;
    const int d0 = tid * 8;
    const int d1 = d0 + 4096;

    int offA[8], offB[4];
#pragma unroll
    for (int i = 0; i < 8; ++i) {
        const int r = wr * 128 + i * 16 + (lane & 15);
        offA[i] = r * 32 + ((((lane >> 4) ^ (r >> 1)) & 3) << 3);
    }
#pragma unroll
    for (int j = 0; j < 4; ++j) {
        const int r = wc * 64 + j * 16 + (lane & 15);
        offB[j] = r * 32 + ((((lane >> 4) ^ (r >> 1)) & 3) << 3);
    }

    f32x4 acc[8][4];
#pragma unroll
    for (int i = 0; i < 8; ++i)
#pragma unroll
        for (int j = 0; j < 4; ++j)
            acc[i][j] = (f32x4){0.f, 0.f, 0.f, 0.f};

#define STG(NB, KB) do {                                                      \
        load_lds16((const u16*)(pAh + aof + (KB)), lds + (NB) + d0);          \
        load_lds16((const u16*)(pAh + ao2 + (KB)), lds + (NB) + d1);          \
        load_lds16((const u16*)(pB + bof + (KB)), lds + (NB) + O_B + d0);     \
        load_lds16((const u16*)(pB + bo2 + (KB)), lds + (NB) + O_B + d1);     \
        if constexpr (SPLIT) {                                                \
            load_lds16((const u16*)(pAl + aof + (KB)), lds + (NB) + O_AL + d0); \
            load_lds16((const u16*)(pAl + ao2 + (KB)), lds + (NB) + O_AL + d1); \
        }                                                                     \
    } while (0)

#define TERM(AF, BF) do {                                                     \
        __builtin_amdgcn_s_setprio(1);                                        \
        _Pragma("unroll")                                                     \
        for (int i = 0; i < 8; ++i)                                           \
            _Pragma("unroll")                                                 \
            for (int j = 0; j < 4; ++j)                                       \
                acc[i][j] = MFMA_F16(AF[i], BF[j], acc[i][j]);                \
        __builtin_amdgcn_s_setprio(0);                                        \
    } while (0)

    constexpr int NT = 32;

    STG(0, 0);

    for (int t = 0; t < NT; ++t) {
        const int cb = (t & 1) ? BUF : 0;
        const int nb = (t & 1) ? 0 : BUF;
        const long long kb = (long long)(t + 1) * 64;

        VMW0();
        SBAR();
        f16x8 b[4], ah[8], al[8];
#pragma unroll
        for (int j = 0; j < 4; ++j)
            b[j] = *(const f16x8*)(lds + cb + O_B + offB[j]);
#pragma unroll
        for (int i = 0; i < 8; ++i)
            ah[i] = *(const f16x8*)(lds + cb + offA[i]);
        if constexpr (SPLIT) {
#pragma unroll
            for (int i = 0; i < 8; ++i)
                al[i] = *(const f16x8*)(lds + cb + O_AL + offA[i]);
        }
        if (t + 1 < NT) STG(nb, kb);
        if constexpr (SPLIT) { LGKM8(); } else { LGKM0(); }
        SCHB();
        TERM(ah, b);
        if constexpr (SPLIT) {
            LGKM0(); SCHB();
            TERM(al, b);
        }
    }
#undef STG
#undef TERM

    const long long Cbase = z * sC;
#pragma unroll
    for (int i = 0; i < 8; ++i) {
        const int row0 = bm + wr * 128 + i * 16 + ((lane >> 4) << 2);
#pragma unroll
        for (int j = 0; j < 4; ++j) {
            const int col = bn + wc * 64 + j * 16 + (lane & 15);
#pragma unroll
            for (int e = 0; e < 4; ++e) {
                const float v = acc[i][j][e];
                const long long idx = Cbase + (long long)(row0 + e) * N + col;
                if constexpr (EPI == 0) {
                    Cf[idx] = v;
                } else if constexpr (EPI == 1) {
                    Ch[idx] = f2h(v + bias[col]);
                } else {
                    Cf[idx] = fmaxf(v, 0.f);
                }
            }
        }
    }
}

// ---------------------------------------------------------------------------
// R19 dense GEMM + R24 coalesced epilogue. K-loop identical to the verified
// 8-phase schedule. Epilogue: per row-block i, waves deposit fragments into
// a padded [2][16][260] f32 LDS tile (pitch 260 = 1040B breaks the 4-way
// write conflict; reads stride-1), then 512 threads stream the 32x256 band
// as contiguous float4 stores (1KB runs; 32 vec stores/thread vs 128
// scalar). relu applied at read-out for EPI=2. Values bit-identical.
// ---------------------------------------------------------------------------
template<int EPI>
__launch_bounds__(512, 2)
__global__ void gemm_p8(const u16* __restrict__ Am, const u16* __restrict__ Bm,
                        float* __restrict__ Cf,
                        int N, int gn, int gmn,
                        long long sA, long long sB, long long sC)
{
    constexpr int OB    = 16384;
    constexpr int BUFSZ = 32768;
    __shared__ __align__(16) u16 lds[2 * BUFSZ];

    const int tid  = threadIdx.x;
    const int lane = tid & 63;
    const int wv   = tid >> 6;
    const int wr   = wv >> 2, wc = wv & 3;

    const int d   = blockIdx.x;
    const int cpx = gridDim.x >> 3;
    const int swz = (d & 7) * cpx + (d >> 3);
    const long long z = swz / gmn;
    const int r_  = swz % gmn;
    const int bm  = (r_ / gn) * 256;
    const int bn  = (r_ % gn) * 256;

    const char* pA = (const char*)(Am + z * sA);
    const char* pB = (const char*)(Bm + z * sB);

    const int rr  = tid >> 3;
    const int xcv = (tid & 7) ^ (rr & 7);
    long long aofs[4], bofs[4];
#pragma unroll
    for (int j = 0; j < 4; ++j) {
        aofs[j] = (long long)(bm + rr + j * 64) * 2048 + xcv * 16;
        bofs[j] = (long long)(bn + rr + j * 64) * 2048 + xcv * 16;
    }

    int offA[8][2], offB[4][2];
#pragma unroll
    for (int i = 0; i < 8; ++i) {
        const int r = wr * 128 + i * 16 + (lane & 15);
#pragma unroll
        for (int s = 0; s < 2; ++s)
            offA[i][s] = r * 64 + ((((s * 4 + (lane >> 4)) ^ r) & 7) << 3);
    }
#pragma unroll
    for (int j = 0; j < 4; ++j) {
        const int r = wc * 64 + j * 16 + (lane & 15);
#pragma unroll
        for (int s = 0; s < 2; ++s)
            offB[j][s] = OB + r * 64 + ((((s * 4 + (lane >> 4)) ^ r) & 7) << 3);
    }

    f32x4 acc[8][4];
#pragma unroll
    for (int i = 0; i < 8; ++i)
#pragma unroll
        for (int j = 0; j < 4; ++j)
            acc[i][j] = (f32x4){0.f, 0.f, 0.f, 0.f};

    f16x8 bb[4][2];

#define STA(NB, J, KB) load_lds16((const u16*)(pA + aofs[J] + (KB)), \
                                  lds + (NB) + tid * 8 + (J) * 4096)
#define STB(NB, J, KB) load_lds16((const u16*)(pB + bofs[J] + (KB)), \
                                  lds + (NB) + OB + tid * 8 + (J) * 4096)
#define RD_BB(CB) do {                                                        \
        _Pragma("unroll")                                                     \
        for (int j = 0; j < 4; ++j) {                                         \
            bb[j][0] = *(const f16x8*)(lds + (CB) + offB[j][0]);              \
            bb[j][1] = *(const f16x8*)(lds + (CB) + offB[j][1]);              \
        }                                                                     \
    } while (0)
#define PHASE(CB, I0, FIRST, STAGES, WAITST) do {                             \
        if (FIRST) RD_BB(CB);                                                 \
        f16x8 a00 = *(const f16x8*)(lds + (CB) + offA[(I0)][0]);              \
        f16x8 a01 = *(const f16x8*)(lds + (CB) + offA[(I0)][1]);              \
        f16x8 a10 = *(const f16x8*)(lds + (CB) + offA[(I0) + 1][0]);          \
        f16x8 a11 = *(const f16x8*)(lds + (CB) + offA[(I0) + 1][1]);          \
        STAGES;                                                               \
        if (FIRST) LGKM8();                                                   \
        SBAR();                                                               \
        LGKM0(); SCHB();                                                      \
        __builtin_amdgcn_s_setprio(1);                                        \
        _Pragma("unroll")                                                     \
        for (int j = 0; j < 4; ++j) {                                         \
            acc[(I0)][j]     = MFMA_F16(a00, bb[j][0], acc[(I0)][j]);         \
            acc[(I0)][j]     = MFMA_F16(a01, bb[j][1], acc[(I0)][j]);         \
            acc[(I0) + 1][j] = MFMA_F16(a10, bb[j][0], acc[(I0) + 1][j]);     \
            acc[(I0) + 1][j] = MFMA_F16(a11, bb[j][1], acc[(I0) + 1][j]);     \
        }                                                                     \
        __builtin_amdgcn_s_setprio(0);                                        \
        WAITST;                                                               \
        SBAR();                                                               \
    } while (0)

    constexpr int NT2 = 8;

    STB(0, 0, 0); STB(0, 1, 0); STB(0, 2, 0); STB(0, 3, 0);
    STA(0, 0, 0); STA(0, 1, 0); STA(0, 2, 0); STA(0, 3, 0);
    STB(BUFSZ, 0, 128); STB(BUFSZ, 1, 128); STB(BUFSZ, 2, 128); STB(BUFSZ, 3, 128);
    VMW4();
    SBAR();

    for (int it = 0; it < NT2; ++it) {
        const long long kb1 = (long long)(2 * it + 1) * 128;
        const long long kb2 = (long long)(2 * it + 2) * 128;
        const long long kb3 = (long long)(2 * it + 3) * 128;
        const bool st2 = (it + 1) < NT2;

        PHASE(0, 0, true,  { STA(BUFSZ, 0, kb1); STA(BUFSZ, 1, kb1); }, );
        PHASE(0, 2, false, { STA(BUFSZ, 2, kb1); STA(BUFSZ, 3, kb1); }, );
        PHASE(0, 4, false, { if (st2) { STB(0, 0, kb2); STB(0, 1, kb2); } }, );
        PHASE(0, 6, false, { if (st2) { STB(0, 2, kb2); STB(0, 3, kb2); } },
              { if (st2) { VMW4(); } else { VMW0(); } });
        PHASE(BUFSZ, 0, true,  { if (st2) { STA(0, 0, kb2); STA(0, 1, kb2); } }, );
        PHASE(BUFSZ, 2, false, { if (st2) { STA(0, 2, kb2); STA(0, 3, kb2); } }, );
        PHASE(BUFSZ, 4, false, { if (st2) { STB(BUFSZ, 0, kb3); STB(BUFSZ, 1, kb3); } }, );
        PHASE(BUFSZ, 6, false, { if (st2) { STB(BUFSZ, 2, kb3); STB(BUFSZ, 3, kb3); } },
              { if (st2) VMW4(); });
    }
#undef STA
#undef STB
#undef RD_BB
#undef PHASE

    // R24 epilogue: LDS-bounce to coalesced float4 stores.
    // Band layout: [band(=wr) 2][row 16][col 260 pitch] f32 = 33.3KB (reuses
    // staging LDS, free after the final lgkmcnt(0)/vmcnt(0) + barrier above).
    float* slds = (float*)lds;
    const long long Cbase = z * sC;
#pragma unroll
    for (int i = 0; i < 8; ++i) {
        // deposit: lane holds (col = wc*64 + j*16 + (lane&15),
        //                      rowInBand = (lane>>4)*4 + e), band = wr.
        const int wbase = wr * 4160 + ((lane >> 4) << 2) * 260;
#pragma unroll
        for (int j = 0; j < 4; ++j) {
            const int c = wc * 64 + j * 16 + (lane & 15);
#pragma unroll
            for (int e = 0; e < 4; ++e)
                slds[wbase + e * 260 + c] = acc[i][j][e];
        }
        SBAR();
        // stream out: 2 bands x 16 rows x 256 cols, float4 per thread x4.
#pragma unroll
        for (int k = 0; k < 4; ++k) {
            const int f = tid + k * 512;            // 0..2047
            const int band = f >> 10;
            const int rib  = (f >> 6) & 15;
            const int c4   = (f & 63) * 4;
            f32x4 v = *(const f32x4*)&slds[band * 4160 + rib * 260 + c4];
            if constexpr (EPI == 2) {
                v[0] = fmaxf(v[0], 0.f); v[1] = fmaxf(v[1], 0.f);
                v[2] = fmaxf(v[2], 0.f); v[3] = fmaxf(v[3], 0.f);
            }
            const long long row = bm + band * 128 + i * 16 + rib;
            *(f32x4*)&Cf[Cbase + row * N + bn + c4] = v;
        }
        SBAR();   // protect slds before next i overwrites
    }
}

// R23: fully-vectorized streaming pre-pass (float4 in, ushort4 out):
// p -> p16; q -> q_hi, q_lo.
__global__ void cvt_pq_vec(const float4* __restrict__ p, const float4* __restrict__ q,
                           ushort4* __restrict__ p16, ushort4* __restrict__ hi,
                           ushort4* __restrict__ lo, long long n4)
{
    const long long i = (long long)blockIdx.x * 256 + threadIdx.x;
    if (i >= n4) return;
    const float4 a = p[i];
    ushort4 hp;
    hp.x = f2h(a.x); hp.y = f2h(a.y); hp.z = f2h(a.z); hp.w = f2h(a.w);
    p16[i] = hp;
    const float4 b = q[i];
    ushort4 hq, lq;
    hq.x = f2h(b.x); lq.x = f2h(b.x - h2f(hq.x));
    hq.y = f2h(b.y); lq.y = f2h(b.y - h2f(hq.y));
    hq.z = f2h(b.z); lq.z = f2h(b.z - h2f(hq.z));
    hq.w = f2h(b.w); lq.w = f2h(b.w - h2f(hq.w));
    hi[i] = hq;
    lo[i] = lq;
}

// R23: fp16 transpose qT[c][r] = q_hi[r][c], per batch z.
__global__ void transpose_h(const u16* __restrict__ in, u16* __restrict__ out)
{
    __shared__ u16 t[64][68];
    const long long base = (long long)blockIdx.z * 1048576;
    const int r0 = blockIdx.y * 64, c0 = blockIdx.x * 64;
    const int tid = threadIdx.x;
    const int rl = tid >> 4;
    const int cl = (tid & 15) * 4;
#pragma unroll
    for (int pp = 0; pp < 4; ++pp) {
        const int r = pp * 16 + rl;
        const ushort4 v = *(const ushort4*)&in[base + (long long)(r0 + r) * 1024 + c0 + cl];
        t[r][cl + 0] = v.x; t[r][cl + 1] = v.y;
        t[r][cl + 2] = v.z; t[r][cl + 3] = v.w;
    }
    __syncthreads();
#pragma unroll
    for (int pp = 0; pp < 4; ++pp) {
        const int c = pp * 16 + rl;
        const int r = cl;
        ushort4 o;
        o.x = t[r + 0][c]; o.y = t[r + 1][c];
        o.z = t[r + 2][c]; o.w = t[r + 3][c];
        *(ushort4*)&out[base + (long long)(c0 + c) * 1024 + r0 + r] = o;
    }
}

// Wt[c][r] = W[r][c], fp16 single
__global__ void transpose_cvt_w(const float* __restrict__ in, u16* __restrict__ hi)
{
    __shared__ float t[32][33];
    const int r0 = blockIdx.y * 32, c0 = blockIdx.x * 32;
    for (int j = threadIdx.y; j < 32; j += 8)
        t[j][threadIdx.x] = in[(long long)(r0 + j) * 1024 + c0 + threadIdx.x];
    __syncthreads();
    for (int j = threadIdx.y; j < 32; j += 8)
        hi[(long long)(c0 + j) * 1024 + r0 + threadIdx.x] = f2h(t[threadIdx.x][j]);
}

// wave-per-row softmax (R22-verified): 64 lanes x 4 float4 = 1024 elems.
__global__ void softmax_wave(const float* __restrict__ S, u16* __restrict__ A)
{
    const int lane = threadIdx.x & 63;
    const long long row = (long long)blockIdx.x * 4 + (threadIdx.x >> 6);
    const float4* rp = (const float4*)(S + row * (long long)LQ_N);
    float4 v[4];
#pragma unroll
    for (int k = 0; k < 4; ++k)
        v[k] = rp[lane + 64 * k];

    float m = -1e30f;
#pragma unroll
    for (int k = 0; k < 4; ++k)
        m = fmaxf(m, fmaxf(fmaxf(v[k].x, v[k].y), fmaxf(v[k].z, v[k].w)));
#pragma unroll
    for (int off = 32; off > 0; off >>= 1)
        m = fmaxf(m, __shfl_xor(m, off));

    float s = 0.f;
#pragma unroll
    for (int k = 0; k < 4; ++k) {
        v[k].x = __expf(v[k].x - m); v[k].y = __expf(v[k].y - m);
        v[k].z = __expf(v[k].z - m); v[k].w = __expf(v[k].w - m);
        s += v[k].x + v[k].y + v[k].z + v[k].w;
    }
#pragma unroll
    for (int off = 32; off > 0; off >>= 1)
        s += __shfl_xor(s, off);

    const float inv = 1.0f / s;
    ushort4* op = (ushort4*)(A + row * (long long)LQ_N);
#pragma unroll
    for (int k = 0; k < 4; ++k) {
        ushort4 o;
        o.x = f2h(v[k].x * inv); o.y = f2h(v[k].y * inv);
        o.z = f2h(v[k].z * inv); o.w = f2h(v[k].w * inv);
        op[lane + 64 * k] = o;
    }
}

// ---------------------------------------------------------------------------
// Fallback fp32 path (round-1, verified; needs only 128 MB ws)
// ---------------------------------------------------------------------------
#define BM 128
#define BN 128
#define BK 8
#define TM 8
#define TN 8

template<bool TRANSB, bool BIAS, bool RELU>
__launch_bounds__(256)
__global__ void gemm_k(const float* __restrict__ A, const float* __restrict__ Bmat,
                       const float* __restrict__ bias, float* __restrict__ C,
                       int M, int N, int K,
                       long long sA, long long sB, long long sC)
{
    __shared__ float As[BK][BM];
    __shared__ float Bs[BK][BN];
    const int tid = threadIdx.x;
    const int tx = tid & 15;
    const int ty = tid >> 4;
    const int bn = blockIdx.x * BN;
    const int bm = blockIdx.y * BM;
    const long long z = blockIdx.z;
    A += z * sA; Bmat += z * sB; C += z * sC;
    float acc[TM][TN];
#pragma unroll
    for (int i = 0; i < TM; i++)
#pragma unroll
        for (int j = 0; j < TN; j++) acc[i][j] = 0.f;
    const int arow = tid >> 1;
    const int acol = (tid & 1) * 4;
    const int bk_n = tid >> 5;
    const int bn_n = (tid & 31) * 4;
    for (int k0 = 0; k0 < K; k0 += BK) {
        float4 a4 = *(const float4*)&A[(long long)(bm + arow) * K + k0 + acol];
        As[acol + 0][arow] = a4.x; As[acol + 1][arow] = a4.y;
        As[acol + 2][arow] = a4.z; As[acol + 3][arow] = a4.w;
        if (TRANSB) {
            float4 b4 = *(const float4*)&Bmat[(long long)(bn + arow) * K + k0 + acol];
            Bs[acol + 0][arow] = b4.x; Bs[acol + 1][arow] = b4.y;
            Bs[acol + 2][arow] = b4.z; Bs[acol + 3][arow] = b4.w;
        } else {
            float4 b4 = *(const float4*)&Bmat[(long long)(k0 + bk_n) * N + bn + bn_n];
            *(float4*)&Bs[bk_n][bn_n] = b4;
        }
        __syncthreads();
#pragma unroll
        for (int k = 0; k < BK; k++) {
            float a[TM], b[TN];
            *(float4*)&a[0] = *(const float4*)&As[k][ty * TM];
            *(float4*)&a[4] = *(const float4*)&As[k][ty * TM + 4];
            *(float4*)&b[0] = *(const float4*)&Bs[k][tx * TN];
            *(float4*)&b[4] = *(const float4*)&Bs[k][tx * TN + 4];
#pragma unroll
            for (int i = 0; i < TM; i++)
#pragma unroll
                for (int j = 0; j < TN; j++)
                    acc[i][j] = fmaf(a[i], b[j], acc[i][j]);
        }
        __syncthreads();
    }
#pragma unroll
    for (int i = 0; i < TM; i++) {
        const int row = bm + ty * TM + i;
#pragma unroll
        for (int j = 0; j < TN; j += 4) {
            const int col = bn + tx * TN + j;
            float4 v;
            v.x = acc[i][j + 0]; v.y = acc[i][j + 1];
            v.z = acc[i][j + 2]; v.w = acc[i][j + 3];
            if (BIAS) {
                v.x += bias[col + 0]; v.y += bias[col + 1];
                v.z += bias[col + 2]; v.w += bias[col + 3];
            }
            if (RELU) {
                v.x = fmaxf(v.x, 0.f); v.y = fmaxf(v.y, 0.f);
                v.z = fmaxf(v.z, 0.f); v.w = fmaxf(v.w, 0.f);
            }
            *(float4*)&C[(long long)row * N + col] = v;
        }
    }
}

__global__ void softmax_k(float* __restrict__ S)
{
    const long long row = blockIdx.x;
    float* r = S + row * (long long)LQ_N;
    const int t = threadIdx.x;
    float4 v = ((float4*)r)[t];
    float m = fmaxf(fmaxf(v.x, v.y), fmaxf(v.z, v.w));
#pragma unroll
    for (int off = 32; off > 0; off >>= 1)
        m = fmaxf(m, __shfl_xor(m, off));
    __shared__ float red[4];
    const int lane = t & 63, wid = t >> 6;
    if (lane == 0) red[wid] = m;
    __syncthreads();
    m = fmaxf(fmaxf(red[0], red[1]), fmaxf(red[2], red[3]));
    __syncthreads();
    v.x = __expf(v.x - m); v.y = __expf(v.y - m);
    v.z = __expf(v.z - m); v.w = __expf(v.w - m);
    float s = v.x + v.y + v.z + v.w;
#pragma unroll
    for (int off = 32; off > 0; off >>= 1)
        s += __shfl_xor(s, off);
    if (lane == 0) red[wid] = s;
    __syncthreads();
    s = red[0] + red[1] + red[2] + red[3];
    const float inv = 1.0f / s;
    v.x *= inv; v.y *= inv; v.z *= inv; v.w *= inv;
    ((float4*)r)[t] = v;
}

extern "C" void kernel_launch(void* const* d_in, const int* in_sizes, int n_in,
                              void* d_out, int out_size, void* d_ws, size_t ws_size,
                              hipStream_t stream)
{
    const float* p    = (const float*)d_in[0];
    const float* q    = (const float*)d_in[1];
    const float* W    = (const float*)d_in[2];
    const float* bias = (const float*)d_in[3];
    float* out = (float*)d_out;

    const size_t MB32 = 33554432ull;                 // 32 MB unit
    const size_t NEED = 5 * MB32 + 2097152ull;       // 162 MB

    if (ws_size >= NEED) {
        char* w = (char*)d_ws;
        u16* p16   = (u16*)(w + 0 * MB32);
        u16* q_hi  = (u16*)(w + 1 * MB32);
        u16* q_lo  = (u16*)(w + 2 * MB32);
        u16* keys  = (u16*)(w + 3 * MB32);
        u16* qT    = (u16*)(w + 4 * MB32);
        u16* Wt    = (u16*)(w + 5 * MB32);
        float* scores = (float*)(w + 1 * MB32);  // reuses q_hi/q_lo after GEMM1
        u16* attn     = (u16*)(w + 0 * MB32);    // reuses p16 after GEMM2

        const long long n4 = (long long)B_N * LQ_N * H_N / 4;
        cvt_pq_vec<<<(unsigned)(n4 / 256), 256, 0, stream>>>(
            (const float4*)p, (const float4*)q,
            (ushort4*)p16, (ushort4*)q_hi, (ushort4*)q_lo, n4);
        transpose_h<<<dim3(16, 16, B_N), 256, 0, stream>>>(q_hi, qT);
        transpose_cvt_w<<<dim3(32, 32, 1), dim3(32, 8), 0, stream>>>(W, Wt);

        // keys = (q_hi + q_lo) @ Wt + b : BK32 split 2-barrier (verified).
        gemm2t<true, 1><<<256, 512, 0, stream>>>(
            q_hi, q_lo, Wt, bias, nullptr, keys,
            H_N, /*gn=*/4, /*gmn=*/256, 0, 0, 0);

        // scores[b] = p16[b] @ keys[b]^T : 8-phase dense + coalesced epilogue.
        gemm_p8<0><<<256, 512, 0, stream>>>(
            p16, keys, scores,
            LQ_N, /*gn=*/4, /*gmn=*/16,
            (long long)LP_N * H_N, (long long)LQ_N * H_N, (long long)LP_N * LQ_N);

        softmax_wave<<<(B_N * LP_N) / 4, 256, 0, stream>>>(scores, attn);

        // out[b] = relu(attn[b] @ q[b]) : 8-phase dense + coalesced epilogue.
        gemm_p8<2><<<256, 512, 0, stream>>>(
            attn, qT, out,
            H_N, /*gn=*/4, /*gmn=*/16,
            (long long)LP_N * LQ_N, (long long)H_N * LQ_N, (long long)LP_N * H_N);
    } else {
        float* keys   = (float*)d_ws;
        float* scores = keys + (long long)B_N * LQ_N * H_N;

        gemm_k<false, true, false><<<dim3(H_N / BN, (B_N * LQ_N) / BM, 1), 256, 0, stream>>>(
            q, W, bias, keys, B_N * LQ_N, H_N, H_N, 0, 0, 0);
        gemm_k<true, false, false><<<dim3(LQ_N / BN, LP_N / BM, B_N), 256, 0, stream>>>(
            p, keys, nullptr, scores, LP_N, LQ_N, H_N,
            (long long)LP_N * H_N, (long long)LQ_N * H_N, (long long)LP_N * LQ_N);
        softmax_k<<<B_N * LP_N, 256, 0, stream>>>(scores);
        gemm_k<false, false, true><<<dim3(H_N / BN, LP_N / BM, B_N), 256, 0, stream>>>(
            scores, q, nullptr, out, LP_N, H_N, LQ_N,
            (long long)LP_N * LQ_N, (long long)LQ_N * H_N, (long long)LP_N * H_N);
    }
}